// Round 1
// baseline (440.755 us; speedup 1.0000x reference)
//
#include <hip/hip_runtime.h>
#include <math.h>

#define HWSZ 65536   // 256*256
#define IMGH 256
#define IMGW 256

// ---------------- K0a: weight re-layouts ----------------
// woffT[(tap*64+c)*28 + d] = w_off[(d*64+c)*9 + tap]   (27 d's, pad row to 28)
// wT[(k*64+c)*64 + o]      = w[(o*64+c)*9 + k]
__global__ void prep_weights(const float* __restrict__ w_off,
                             const float* __restrict__ w,
                             float* __restrict__ woffT,
                             float* __restrict__ wT) {
    int i = blockIdx.x * 256 + threadIdx.x;
    if (i < 27 * 64 * 9) {
        int tap = i % 9;
        int c   = (i / 9) % 64;
        int d   = i / (9 * 64);
        woffT[(tap * 64 + c) * 28 + d] = w_off[(d * 64 + c) * 9 + tap];
    }
    if (i < 9 * 64 * 64) {
        int k = i / (64 * 64);
        int c = (i / 64) % 64;
        int o = i % 64;
        wT[(k * 64 + c) * 64 + o] = w[(o * 64 + c) * 9 + k];
    }
}

// ---------------- K0b: x NCHW -> NHWC ----------------
__global__ __launch_bounds__(256) void transpose_x(const float* __restrict__ x,
                                                   float* __restrict__ xT) {
    __shared__ float tile[64 * 65];
    int blk = blockIdx.x;              // 2048 = 2 * 1024
    int b = blk >> 10;
    int p0 = (blk & 1023) * 64;
    int t = threadIdx.x;
    const float* xb = x + (size_t)b * 64 * HWSZ;
    float* xTb = xT + (size_t)b * HWSZ * 64;
    int pp = t & 63;
    int c0 = t >> 6;
#pragma unroll
    for (int i = 0; i < 16; ++i) {
        int c = c0 + 4 * i;
        tile[c * 65 + pp] = xb[(size_t)c * HWSZ + p0 + pp];
    }
    __syncthreads();
    int c = t & 63;
    int pr = t >> 6;
#pragma unroll
    for (int i = 0; i < 16; ++i) {
        int p = pr + 4 * i;
        xTb[(size_t)(p0 + p) * 64 + c] = tile[c * 65 + p];
    }
}

// ---------------- K1: offset conv -> om[b][d][p] (raw, +b_off) ----------------
__global__ __launch_bounds__(256) void offset_conv(const float* __restrict__ xT,
                                                   const float* __restrict__ woffT,
                                                   const float* __restrict__ b_off,
                                                   float* __restrict__ om) {
    __shared__ float xt[10 * 10 * 68];
    int blk = blockIdx.x;              // 2048
    int b = blk >> 10;
    int tb = blk & 1023;
    int ty = tb >> 5, tx = tb & 31;
    int h0 = ty * 8, w0 = tx * 8;
    int t = threadIdx.x;
    const float* xTb = xT + (size_t)b * HWSZ * 64;

    // stage 10x10x64 halo (zeros outside image)
    for (int idx = t; idx < 6400; idx += 256) {
        int r = idx / 640;
        int rem = idx - r * 640;
        int s = rem >> 6;
        int c = rem & 63;
        int y = h0 - 1 + r;
        int xc = w0 - 1 + s;
        float v = 0.f;
        if (y >= 0 && y < IMGH && xc >= 0 && xc < IMGW)
            v = xTb[(size_t)(y * IMGW + xc) * 64 + c];
        xt[(r * 10 + s) * 68 + c] = v;
    }
    __syncthreads();

    int wid = __builtin_amdgcn_readfirstlane(t >> 6);
    int lane = t & 63;
    int d0 = wid * 7;                  // wave 3 only uses 6 (d=21..26)
    int py = lane >> 3, px = lane & 7;
    float acc[7];
#pragma unroll
    for (int j = 0; j < 7; ++j) acc[j] = 0.f;

    for (int tap = 0; tap < 9; ++tap) {
        int dy = tap / 3, dx = tap % 3;
        int cellbase = ((py + dy) * 10 + (px + dx)) * 68;
        const float* wrow = woffT + (size_t)tap * 64 * 28;
#pragma unroll 4
        for (int c = 0; c < 64; c += 4) {
            float vv[4];
            *(float4*)vv = *(const float4*)&xt[cellbase + c];
#pragma unroll
            for (int j = 0; j < 4; ++j) {
                float xv = vv[j];
                const float* wc = wrow + (c + j) * 28 + d0;
#pragma unroll
                for (int dd = 0; dd < 7; ++dd)   // wave3: acc[6] garbage, discarded
                    acc[dd] = fmaf(wc[dd], xv, acc[dd]);
            }
        }
    }
    int gp = (h0 + py) * IMGW + (w0 + px);
#pragma unroll
    for (int dd = 0; dd < 7; ++dd) {
        int d = d0 + dd;
        if (d < 27)
            om[((size_t)(b * 27 + d)) * HWSZ + gp] = acc[dd] + b_off[d];
    }
}

// ---------------- K2: deformable sample + einsum -> pre-BN out (NCHW) ----------------
__global__ __launch_bounds__(256) void dcn_main(const float* __restrict__ xT,
                                                const float* __restrict__ om,
                                                const float* __restrict__ wT,
                                                const float* __restrict__ bias,
                                                float* __restrict__ out) {
    __shared__ float S[64 * 65];
    __shared__ float prmw[64][4];
    __shared__ int prmi[64][4];
    int blk = blockIdx.x;              // 2048
    int b = blk >> 10;
    int tb = blk & 1023;
    int ty = tb >> 5, tx = tb & 31;
    int h0 = ty * 8, w0 = tx * 8;
    int t = threadIdx.x;
    const float* xTb = xT + (size_t)b * HWSZ * 64;
    const float* omb = om + (size_t)b * 27 * HWSZ;
    int lane = t & 63;
    int wid4 = t >> 6;
    int o0 = __builtin_amdgcn_readfirstlane(wid4) * 16;
    float acc[16];
#pragma unroll
    for (int j = 0; j < 16; ++j) acc[j] = 0.f;

    for (int k = 0; k < 9; ++k) {
        // ---- per-pixel params (threads 0..63) ----
        if (t < 64) {
            int p = t;
            int h = h0 + (p >> 3), wc = w0 + (p & 7);
            int gp = h * IMGW + wc;
            float offy = omb[(size_t)k * HWSZ + gp];
            float offx = omb[(size_t)(k + 9) * HWSZ + gp];
            float mraw = omb[(size_t)(k + 18) * HWSZ + gp];
            float m = 1.f / (1.f + __expf(-mraw));
            float pyf = (float)h + (float)(k / 3 - 1) + offy;
            float pxf = (float)wc + (float)(k % 3 - 1) + offx;
            float y0f = floorf(pyf), x0f = floorf(pxf);
            float wy = pyf - y0f, wx = pxf - x0f;
            int y0 = (int)y0f, x0 = (int)x0f;
            int y1 = y0 + 1, x1 = x0 + 1;
            float vy0 = (y0 >= 0 && y0 < IMGH) ? 1.f : 0.f;
            float vy1 = (y1 >= 0 && y1 < IMGH) ? 1.f : 0.f;
            float vx0 = (x0 >= 0 && x0 < IMGW) ? 1.f : 0.f;
            float vx1 = (x1 >= 0 && x1 < IMGW) ? 1.f : 0.f;
            int y0c = min(max(y0, 0), IMGH - 1), y1c = min(max(y1, 0), IMGH - 1);
            int x0c = min(max(x0, 0), IMGW - 1), x1c = min(max(x1, 0), IMGW - 1);
            prmw[p][0] = (1.f - wy) * (1.f - wx) * m * vy0 * vx0;
            prmw[p][1] = (1.f - wy) * wx * m * vy0 * vx1;
            prmw[p][2] = wy * (1.f - wx) * m * vy1 * vx0;
            prmw[p][3] = wy * wx * m * vy1 * vx1;
            prmi[p][0] = (y0c * IMGW + x0c) * 64;
            prmi[p][1] = (y0c * IMGW + x1c) * 64;
            prmi[p][2] = (y1c * IMGW + x0c) * 64;
            prmi[p][3] = (y1c * IMGW + x1c) * 64;
        }
        __syncthreads();
        // ---- build S[c][p] = mask * bilinear(x[.,c]) ----
        {
            int c = lane;
#pragma unroll 4
            for (int i = 0; i < 16; ++i) {
                int p = wid4 + 4 * i;
                float v = prmw[p][0] * xTb[prmi[p][0] + c]
                        + prmw[p][1] * xTb[prmi[p][1] + c]
                        + prmw[p][2] * xTb[prmi[p][2] + c]
                        + prmw[p][3] * xTb[prmi[p][3] + c];
                S[c * 65 + p] = v;
            }
        }
        __syncthreads();
        // ---- GEMM: acc[o] += sum_c wT[k][c][o] * S[c][p] ----
        {
            const float* wk = wT + (size_t)k * 64 * 64 + o0;
            for (int cc = 0; cc < 64; ++cc) {
                float sv = S[cc * 65 + lane];
                const float* wrow = wk + cc * 64;
#pragma unroll
                for (int j = 0; j < 16; ++j)
                    acc[j] = fmaf(wrow[j], sv, acc[j]);
            }
        }
        __syncthreads();
    }
    // ---- epilogue: pre-BN out (NCHW) ----
    int h = h0 + (lane >> 3), wc = w0 + (lane & 7);
    size_t gp = (size_t)h * IMGW + wc;
#pragma unroll
    for (int j = 0; j < 16; ++j) {
        int o = o0 + j;
        out[((size_t)(b * 64 + o)) * HWSZ + gp] = acc[j] + bias[o];
    }
}

// ---------------- K3: BN stats (sum, sumsq per channel) ----------------
__global__ __launch_bounds__(256) void bn_stats(const float* __restrict__ out,
                                                float* __restrict__ stats) {
    __shared__ float rs[256], rs2[256];
    int blk = blockIdx.x;              // 1024 = 64 ch * 16 chunks
    int o = blk >> 4;
    int chunk = blk & 15;
    int t = threadIdx.x;
    float s = 0.f, s2 = 0.f;
    for (int i = t; i < 8192; i += 256) {
        int e = chunk * 8192 + i;      // 0..131071
        int b = e >> 16;
        int p = e & 65535;
        float v = out[((size_t)(b * 64 + o)) * HWSZ + p];
        s += v;
        s2 += v * v;
    }
    rs[t] = s; rs2[t] = s2;
    __syncthreads();
    for (int off = 128; off > 0; off >>= 1) {
        if (t < off) { rs[t] += rs[t + off]; rs2[t] += rs2[t + off]; }
        __syncthreads();
    }
    if (t == 0) {
        atomicAdd(&stats[o], rs[0]);
        atomicAdd(&stats[64 + o], rs2[0]);
    }
}

// ---------------- K4: normalize + relu + residual ----------------
__global__ __launch_bounds__(256) void bn_finalize(const float* __restrict__ stats,
                                                   const float* __restrict__ gamma,
                                                   const float* __restrict__ beta,
                                                   const float* __restrict__ x,
                                                   float* __restrict__ out) {
    int f = blockIdx.x * 256 + threadIdx.x;     // float4 index, 2097152 total
    int o = (f >> 14) & 63;
    const float inv_n = 1.f / 131072.f;
    float mean = stats[o] * inv_n;
    float var = stats[64 + o] * inv_n - mean * mean;
    float rstd = rsqrtf(var + 1e-5f);
    float g = gamma[o] * rstd;
    float bb = beta[o] - mean * g;
    float4 v = ((const float4*)out)[f];
    float4 xv = ((const float4*)x)[f];
    float4 r;
    r.x = fmaxf(v.x * g + bb, 0.f) + xv.x;
    r.y = fmaxf(v.y * g + bb, 0.f) + xv.y;
    r.z = fmaxf(v.z * g + bb, 0.f) + xv.z;
    r.w = fmaxf(v.w * g + bb, 0.f) + xv.w;
    ((float4*)out)[f] = r;
}

extern "C" void kernel_launch(void* const* d_in, const int* in_sizes, int n_in,
                              void* d_out, int out_size, void* d_ws, size_t ws_size,
                              hipStream_t stream) {
    const float* x     = (const float*)d_in[0];
    const float* w_off = (const float*)d_in[1];
    const float* b_off = (const float*)d_in[2];
    const float* w     = (const float*)d_in[3];
    const float* bias  = (const float*)d_in[4];
    const float* gamma = (const float*)d_in[5];
    const float* beta  = (const float*)d_in[6];
    float* out = (float*)d_out;
    float* ws = (float*)d_ws;

    float* xT    = ws;                       // 8,388,608 floats (B*HW*C)
    float* om    = xT + 8388608;             // 3,538,944 floats (B*27*HW)
    float* woffT = om + 3538944;             // 16,128 floats
    float* wT    = woffT + 16128;            // 36,864 floats
    float* stats = wT + 36864;               // 128 floats
    // total ~47.9 MB of ws

    hipMemsetAsync(stats, 0, 128 * sizeof(float), stream);
    prep_weights<<<144, 256, 0, stream>>>(w_off, w, woffT, wT);
    transpose_x<<<2048, 256, 0, stream>>>(x, xT);
    offset_conv<<<2048, 256, 0, stream>>>(xT, woffT, b_off, om);
    dcn_main<<<2048, 256, 0, stream>>>(xT, om, wT, bias, out);
    bn_stats<<<1024, 256, 0, stream>>>(out, stats);
    bn_finalize<<<8192, 256, 0, stream>>>(stats, gamma, beta, x, out);
}

// Round 2
// 265.437 us; speedup vs baseline: 1.6605x; 1.6605x over previous
//
#include <hip/hip_runtime.h>
#include <math.h>

#define HWSZ 65536   // 256*256
#define IMGH 256
#define IMGW 256

typedef short short8 __attribute__((ext_vector_type(8)));
typedef float f32x4 __attribute__((ext_vector_type(4)));

__device__ inline unsigned short f2bf(float f) {
    unsigned u = __float_as_uint(f);
    return (unsigned short)((u + 0x7fffu + ((u >> 16) & 1u)) >> 16);
}

__device__ inline void acc_corner(const uint4 q, float w, float* v) {
    v[0] += w * __uint_as_float(q.x << 16);
    v[1] += w * __uint_as_float(q.x & 0xffff0000u);
    v[2] += w * __uint_as_float(q.y << 16);
    v[3] += w * __uint_as_float(q.y & 0xffff0000u);
    v[4] += w * __uint_as_float(q.z << 16);
    v[5] += w * __uint_as_float(q.z & 0xffff0000u);
    v[6] += w * __uint_as_float(q.w << 16);
    v[7] += w * __uint_as_float(q.w & 0xffff0000u);
}

// ---------------- K0a: pack MFMA A-fragments (bf16) ----------------
// wApack  : [g=0..3][tap=0..8][kk=0..1][lane=0..63][j=0..7]  (36864)
//           value = w[(o*64+c)*9+tap], o=g*16+(lane&15), c=kk*32+((lane>>4)&3)*8+j
// wOffPack: [mt=0..1][tap][kk][lane][j]                      (18432)
//           value = w_off[(d*64+c)*9+tap], d=mt*16+(lane&15) (0 if d>=27)
__global__ void prep_weights(const float* __restrict__ w_off,
                             const float* __restrict__ w,
                             unsigned short* __restrict__ wApack,
                             unsigned short* __restrict__ wOffPack) {
    int i = blockIdx.x * 256 + threadIdx.x;
    if (i < 36864) {
        int e = i;
        int j = e & 7, lane = (e >> 3) & 63, kk = (e >> 9) & 1;
        int t2 = e >> 10;
        int tap = t2 % 9, g = t2 / 9;
        int o = g * 16 + (lane & 15);
        int c = kk * 32 + ((lane >> 4) & 3) * 8 + j;
        wApack[e] = f2bf(w[(o * 64 + c) * 9 + tap]);
    } else if (i < 36864 + 18432) {
        int e = i - 36864;
        int j = e & 7, lane = (e >> 3) & 63, kk = (e >> 9) & 1;
        int t2 = e >> 10;
        int tap = t2 % 9, mt = t2 / 9;
        int d = mt * 16 + (lane & 15);
        int c = kk * 32 + ((lane >> 4) & 3) * 8 + j;
        float v = (d < 27) ? w_off[(d * 64 + c) * 9 + tap] : 0.f;
        wOffPack[e] = f2bf(v);
    }
}

// ---------------- K0b: x NCHW fp32 -> NHWC bf16 ----------------
__global__ __launch_bounds__(256) void transpose_x(const float* __restrict__ x,
                                                   unsigned short* __restrict__ xT) {
    __shared__ float tile[64 * 65];
    int blk = blockIdx.x;              // 2048 = 2 * 1024
    int b = blk >> 10;
    int p0 = (blk & 1023) * 64;
    int t = threadIdx.x;
    const float* xb = x + (size_t)b * 64 * HWSZ;
    unsigned short* xTb = xT + (size_t)b * HWSZ * 64;
    int pp = t & 63;
    int c0r = t >> 6;
#pragma unroll
    for (int i = 0; i < 16; ++i) {
        int c = c0r + 4 * i;
        tile[c * 65 + pp] = xb[(size_t)c * HWSZ + p0 + pp];
    }
    __syncthreads();
#pragma unroll
    for (int it = 0; it < 2; ++it) {
        int item = t + it * 256;       // 512 items
        int p = item >> 3;
        int c0 = (item & 7) * 8;
        uint4 ow;
        ow.x = f2bf(tile[(c0 + 0) * 65 + p]) | ((unsigned)f2bf(tile[(c0 + 1) * 65 + p]) << 16);
        ow.y = f2bf(tile[(c0 + 2) * 65 + p]) | ((unsigned)f2bf(tile[(c0 + 3) * 65 + p]) << 16);
        ow.z = f2bf(tile[(c0 + 4) * 65 + p]) | ((unsigned)f2bf(tile[(c0 + 5) * 65 + p]) << 16);
        ow.w = f2bf(tile[(c0 + 6) * 65 + p]) | ((unsigned)f2bf(tile[(c0 + 7) * 65 + p]) << 16);
        *(uint4*)&xTb[(size_t)(p0 + p) * 64 + c0] = ow;
    }
}

// ---------------- K1: offset conv via MFMA -> om[b][d][p] ----------------
__global__ __launch_bounds__(256) void offset_conv(const unsigned short* __restrict__ xT,
                                                   const unsigned short* __restrict__ wOffPack,
                                                   const float* __restrict__ b_off,
                                                   float* __restrict__ om) {
    __shared__ uint4 haloBuf[800];     // 10x10 cells x 64ch bf16, swizzled
    char* halo = (char*)haloBuf;
    int blk = blockIdx.x;              // 2048
    int b = blk >> 10;
    int tb = blk & 1023;
    int ty = tb >> 5, tx = tb & 31;
    int h0 = ty * 8, w0 = tx * 8;
    int t = threadIdx.x;
    const char* xbb = (const char*)(xT + (size_t)b * HWSZ * 64);

    // stage halo (bf16 direct copy, zero OOB), swizzled slots
    for (int i = t; i < 800; i += 256) {
        int cell = i >> 3;
        int c0 = (i & 7) * 8;
        int r = cell / 10, s = cell - r * 10;
        int y = h0 - 1 + r, xx = w0 - 1 + s;
        uint4 v = {0u, 0u, 0u, 0u};
        if (y >= 0 && y < IMGH && xx >= 0 && xx < IMGW)
            v = *(const uint4*)(xbb + ((size_t)(y * IMGW + xx) << 7) + (c0 << 1));
        *(uint4*)(halo + (cell << 7) + (((c0 << 1)) ^ ((cell & 7) << 4))) = v;
    }
    __syncthreads();

    int lane = t & 63;
    int wid = __builtin_amdgcn_readfirstlane(t >> 6);
    int mt = wid & 1;                  // M-tile: d rows mt*16..+15
    int np = wid >> 1;                 // n-pair: pixels tiles {2np, 2np+1}
    f32x4 z = {0.f, 0.f, 0.f, 0.f};
    f32x4 acc[2] = {z, z};
    int lhi = lane >> 4;               // 0..3

    for (int tap = 0; tap < 9; ++tap) {
        const short8* ap = (const short8*)wOffPack;
        short8 a0 = ap[((mt * 9 + tap) * 2 + 0) * 64 + lane];
        short8 a1 = ap[((mt * 9 + tap) * 2 + 1) * 64 + lane];
        int dy = tap / 3, dx = tap - dy * 3;
#pragma unroll
        for (int nn = 0; nn < 2; ++nn) {
            int p = (np * 2 + nn) * 16 + (lane & 15);
            int cell = ((p >> 3) + dy) * 10 + (p & 7) + dx;
            int base = (cell << 7);
            int swz = (cell & 7) << 4;
            short8 b0 = *(const short8*)(halo + base + (((0 * 4 + lhi) << 4) ^ swz));
            acc[nn] = __builtin_amdgcn_mfma_f32_16x16x32_bf16(a0, b0, acc[nn], 0, 0, 0);
            short8 b1 = *(const short8*)(halo + base + (((1 * 4 + lhi) << 4) ^ swz));
            acc[nn] = __builtin_amdgcn_mfma_f32_16x16x32_bf16(a1, b1, acc[nn], 0, 0, 0);
        }
    }
    // epilogue
    float* omb = om + (size_t)b * 27 * HWSZ;
#pragma unroll
    for (int nn = 0; nn < 2; ++nn) {
#pragma unroll
        for (int jj = 0; jj < 4; ++jj) {
            int d = mt * 16 + lhi * 4 + jj;
            if (d < 27) {
                int p = (np * 2 + nn) * 16 + (lane & 15);
                int gp = (h0 + (p >> 3)) * IMGW + w0 + (p & 7);
                omb[(size_t)d * HWSZ + gp] = acc[nn][jj] + b_off[d];
            }
        }
    }
}

// ---------------- K2: deformable sample + MFMA einsum + BN-stats ----------------
__global__ __launch_bounds__(256) void dcn_main(const unsigned short* __restrict__ xT,
                                                const float* __restrict__ om,
                                                const unsigned short* __restrict__ wApack,
                                                unsigned short* __restrict__ preout,
                                                float* __restrict__ stats) {
    __shared__ uint4 SpBuf[512];       // 64px x 64ch bf16, swizzled
    __shared__ float prmw[9][64][4];
    __shared__ int prmi[9][64][4];
    char* sp = (char*)SpBuf;
    int blk = blockIdx.x;              // 2048
    int b = blk >> 10;
    int tb = blk & 1023;
    int ty = tb >> 5, tx = tb & 31;
    int h0 = ty * 8, w0 = tx * 8;
    int t = threadIdx.x;
    const char* xbb = (const char*)(xT + (size_t)b * HWSZ * 64);
    const float* omb = om + (size_t)b * 27 * HWSZ;
    int lane = t & 63;
    int wid = __builtin_amdgcn_readfirstlane(t >> 6);
    int lhi = lane >> 4;

    // phase 0: all 9 taps' bilinear params
    for (int i = t; i < 576; i += 256) {
        int tap = i >> 6, p = i & 63;
        int h = h0 + (p >> 3), wc = w0 + (p & 7);
        int gp = h * IMGW + wc;
        float offy = omb[(size_t)tap * HWSZ + gp];
        float offx = omb[(size_t)(tap + 9) * HWSZ + gp];
        float mraw = omb[(size_t)(tap + 18) * HWSZ + gp];
        float m = 1.f / (1.f + __expf(-mraw));
        float pyf = (float)(h + tap / 3 - 1) + offy;
        float pxf = (float)(wc + tap % 3 - 1) + offx;
        float y0f = floorf(pyf), x0f = floorf(pxf);
        float wy = pyf - y0f, wx = pxf - x0f;
        int y0 = (int)y0f, x0 = (int)x0f;
        int y1 = y0 + 1, x1 = x0 + 1;
        float vy0 = (y0 >= 0 && y0 < IMGH) ? 1.f : 0.f;
        float vy1 = (y1 >= 0 && y1 < IMGH) ? 1.f : 0.f;
        float vx0 = (x0 >= 0 && x0 < IMGW) ? 1.f : 0.f;
        float vx1 = (x1 >= 0 && x1 < IMGW) ? 1.f : 0.f;
        int y0c = min(max(y0, 0), IMGH - 1), y1c = min(max(y1, 0), IMGH - 1);
        int x0c = min(max(x0, 0), IMGW - 1), x1c = min(max(x1, 0), IMGW - 1);
        prmw[tap][p][0] = (1.f - wy) * (1.f - wx) * m * vy0 * vx0;
        prmw[tap][p][1] = (1.f - wy) * wx * m * vy0 * vx1;
        prmw[tap][p][2] = wy * (1.f - wx) * m * vy1 * vx0;
        prmw[tap][p][3] = wy * wx * m * vy1 * vx1;
        prmi[tap][p][0] = (y0c * IMGW + x0c) << 7;
        prmi[tap][p][1] = (y0c * IMGW + x1c) << 7;
        prmi[tap][p][2] = (y1c * IMGW + x0c) << 7;
        prmi[tap][p][3] = (y1c * IMGW + x1c) << 7;
    }
    __syncthreads();

    f32x4 z = {0.f, 0.f, 0.f, 0.f};
    f32x4 acc[4] = {z, z, z, z};
    const short8* ap = (const short8*)wApack;

    for (int tap = 0; tap < 9; ++tap) {
        short8 a0 = ap[((wid * 9 + tap) * 2 + 0) * 64 + lane];
        short8 a1 = ap[((wid * 9 + tap) * 2 + 1) * 64 + lane];
        // build Sp (bf16, swizzled)
#pragma unroll
        for (int it = 0; it < 2; ++it) {
            int i = t + it * 256;      // 512 items
            int p = i >> 3;
            int c0 = (i & 7) * 8;
            float4 wv = *(float4*)&prmw[tap][p][0];
            int4 ip = *(int4*)&prmi[tap][p][0];
            float v[8] = {0.f, 0.f, 0.f, 0.f, 0.f, 0.f, 0.f, 0.f};
            uint4 q0 = *(const uint4*)(xbb + ip.x + (c0 << 1));
            uint4 q1 = *(const uint4*)(xbb + ip.y + (c0 << 1));
            uint4 q2 = *(const uint4*)(xbb + ip.z + (c0 << 1));
            uint4 q3 = *(const uint4*)(xbb + ip.w + (c0 << 1));
            acc_corner(q0, wv.x, v);
            acc_corner(q1, wv.y, v);
            acc_corner(q2, wv.z, v);
            acc_corner(q3, wv.w, v);
            uint4 ow;
            ow.x = f2bf(v[0]) | ((unsigned)f2bf(v[1]) << 16);
            ow.y = f2bf(v[2]) | ((unsigned)f2bf(v[3]) << 16);
            ow.z = f2bf(v[4]) | ((unsigned)f2bf(v[5]) << 16);
            ow.w = f2bf(v[6]) | ((unsigned)f2bf(v[7]) << 16);
            *(uint4*)(sp + (p << 7) + ((c0 << 1) ^ ((p & 7) << 4))) = ow;
        }
        __syncthreads();
        // MFMA: acc[n] over 4 pixel tiles
        int swz = (lane & 7) << 4;
#pragma unroll
        for (int n = 0; n < 4; ++n) {
            int rowb = (n * 16 + (lane & 15)) << 7;
            short8 b0 = *(const short8*)(sp + rowb + (((0 * 4 + lhi) << 4) ^ swz));
            acc[n] = __builtin_amdgcn_mfma_f32_16x16x32_bf16(a0, b0, acc[n], 0, 0, 0);
            short8 b1 = *(const short8*)(sp + rowb + (((1 * 4 + lhi) << 4) ^ swz));
            acc[n] = __builtin_amdgcn_mfma_f32_16x16x32_bf16(a1, b1, acc[n], 0, 0, 0);
        }
        __syncthreads();
    }

    // epilogue: preout (bf16, NCHW) + fused BN partial stats
    unsigned short* pob = preout + (size_t)b * 64 * HWSZ;
#pragma unroll
    for (int n = 0; n < 4; ++n) {
#pragma unroll
        for (int jj = 0; jj < 4; ++jj) {
            int o = wid * 16 + lhi * 4 + jj;
            int p = n * 16 + (lane & 15);
            int gp = (h0 + (p >> 3)) * IMGW + w0 + (p & 7);
            pob[(size_t)o * HWSZ + gp] = f2bf(acc[n][jj]);
        }
    }
#pragma unroll
    for (int jj = 0; jj < 4; ++jj) {
        float s1 = acc[0][jj] + acc[1][jj] + acc[2][jj] + acc[3][jj];
        float s2 = acc[0][jj] * acc[0][jj] + acc[1][jj] * acc[1][jj]
                 + acc[2][jj] * acc[2][jj] + acc[3][jj] * acc[3][jj];
#pragma unroll
        for (int mask = 1; mask < 16; mask <<= 1) {
            s1 += __shfl_xor(s1, mask);
            s2 += __shfl_xor(s2, mask);
        }
        if ((lane & 15) == 0) {
            int o = wid * 16 + lhi * 4 + jj;
            atomicAdd(&stats[o], s1);
            atomicAdd(&stats[64 + o], s2);
        }
    }
}

// ---------------- K3: normalize + relu + residual ----------------
__global__ __launch_bounds__(256) void bn_finalize(const float* __restrict__ stats,
                                                   const float* __restrict__ gamma,
                                                   const float* __restrict__ beta,
                                                   const float* __restrict__ x,
                                                   const unsigned short* __restrict__ preout,
                                                   float* __restrict__ out) {
    int i = blockIdx.x * 256 + threadIdx.x;     // uint4 idx over 8.4M bf16 (1048576)
    int e0 = i * 8;
    int o = (e0 >> 16) & 63;
    const float inv_n = 1.f / 131072.f;
    float mean = stats[o] * inv_n;
    float var = stats[64 + o] * inv_n - mean * mean;
    float rstd = rsqrtf(var + 1e-5f);
    float g = gamma[o] * rstd;
    float bb = beta[o] - mean * g;
    uint4 q = ((const uint4*)preout)[i];
    float4 x0 = ((const float4*)x)[i * 2];
    float4 x1 = ((const float4*)x)[i * 2 + 1];
    float4 r0, r1;
    r0.x = fmaxf(__uint_as_float(q.x << 16) * g + bb, 0.f) + x0.x;
    r0.y = fmaxf(__uint_as_float(q.x & 0xffff0000u) * g + bb, 0.f) + x0.y;
    r0.z = fmaxf(__uint_as_float(q.y << 16) * g + bb, 0.f) + x0.z;
    r0.w = fmaxf(__uint_as_float(q.y & 0xffff0000u) * g + bb, 0.f) + x0.w;
    r1.x = fmaxf(__uint_as_float(q.z << 16) * g + bb, 0.f) + x1.x;
    r1.y = fmaxf(__uint_as_float(q.z & 0xffff0000u) * g + bb, 0.f) + x1.y;
    r1.z = fmaxf(__uint_as_float(q.w << 16) * g + bb, 0.f) + x1.z;
    r1.w = fmaxf(__uint_as_float(q.w & 0xffff0000u) * g + bb, 0.f) + x1.w;
    ((float4*)out)[i * 2] = r0;
    ((float4*)out)[i * 2 + 1] = r1;
}

extern "C" void kernel_launch(void* const* d_in, const int* in_sizes, int n_in,
                              void* d_out, int out_size, void* d_ws, size_t ws_size,
                              hipStream_t stream) {
    const float* x     = (const float*)d_in[0];
    const float* w_off = (const float*)d_in[1];
    const float* b_off = (const float*)d_in[2];
    const float* w     = (const float*)d_in[3];
    const float* gamma = (const float*)d_in[5];
    const float* beta  = (const float*)d_in[6];
    float* out = (float*)d_out;
    char* wsb = (char*)d_ws;

    unsigned short* xT       = (unsigned short*)wsb;                    // 16,777,216 B
    float*          om       = (float*)(wsb + 16777216);                // 14,155,776 B
    unsigned short* preout   = (unsigned short*)(wsb + 30932992);       // 16,777,216 B
    unsigned short* wApack   = (unsigned short*)(wsb + 47710208);       // 73,728 B
    unsigned short* wOffPack = (unsigned short*)(wsb + 47783936);       // 36,864 B
    float*          stats    = (float*)(wsb + 47820800);                // 512 B

    hipMemsetAsync(stats, 0, 512, stream);
    prep_weights<<<216, 256, 0, stream>>>(w_off, w, wApack, wOffPack);
    transpose_x<<<2048, 256, 0, stream>>>(x, xT);
    offset_conv<<<2048, 256, 0, stream>>>(xT, wOffPack, b_off, om);
    dcn_main<<<2048, 256, 0, stream>>>(xT, om, wApack, preout, stats);
    bn_finalize<<<4096, 256, 0, stream>>>(stats, gamma, beta, x, preout, out);
}

// Round 3
// 259.603 us; speedup vs baseline: 1.6978x; 1.0225x over previous
//
#include <hip/hip_runtime.h>
#include <math.h>

#define HWSZ 65536   // 256*256
#define IMGH 256
#define IMGW 256

typedef short short8 __attribute__((ext_vector_type(8)));
typedef float f32x4 __attribute__((ext_vector_type(4)));

__device__ inline unsigned short f2bf(float f) {
    unsigned u = __float_as_uint(f);
    return (unsigned short)((u + 0x7fffu + ((u >> 16) & 1u)) >> 16);
}

__device__ inline void acc_corner(const uint4 q, float w, float* v) {
    v[0] += w * __uint_as_float(q.x << 16);
    v[1] += w * __uint_as_float(q.x & 0xffff0000u);
    v[2] += w * __uint_as_float(q.y << 16);
    v[3] += w * __uint_as_float(q.y & 0xffff0000u);
    v[4] += w * __uint_as_float(q.z << 16);
    v[5] += w * __uint_as_float(q.z & 0xffff0000u);
    v[6] += w * __uint_as_float(q.w << 16);
    v[7] += w * __uint_as_float(q.w & 0xffff0000u);
}

// ---------------- K0a: pack MFMA A-fragments (bf16) ----------------
__global__ void prep_weights(const float* __restrict__ w_off,
                             const float* __restrict__ w,
                             unsigned short* __restrict__ wApack,
                             unsigned short* __restrict__ wOffPack) {
    int i = blockIdx.x * 256 + threadIdx.x;
    if (i < 36864) {
        int e = i;
        int j = e & 7, lane = (e >> 3) & 63, kk = (e >> 9) & 1;
        int t2 = e >> 10;
        int tap = t2 % 9, g = t2 / 9;
        int o = g * 16 + (lane & 15);
        int c = kk * 32 + ((lane >> 4) & 3) * 8 + j;
        wApack[e] = f2bf(w[(o * 64 + c) * 9 + tap]);
    } else if (i < 36864 + 18432) {
        int e = i - 36864;
        int j = e & 7, lane = (e >> 3) & 63, kk = (e >> 9) & 1;
        int t2 = e >> 10;
        int tap = t2 % 9, mt = t2 / 9;
        int d = mt * 16 + (lane & 15);
        int c = kk * 32 + ((lane >> 4) & 3) * 8 + j;
        float v = (d < 27) ? w_off[(d * 64 + c) * 9 + tap] : 0.f;
        wOffPack[e] = f2bf(v);
    }
}

// ---------------- K0b: x NCHW fp32 -> NHWC bf16 ----------------
__global__ __launch_bounds__(256) void transpose_x(const float* __restrict__ x,
                                                   unsigned short* __restrict__ xT) {
    __shared__ float tile[64 * 65];
    int blk = blockIdx.x;              // 2048 = 2 * 1024
    int b = blk >> 10;
    int p0 = (blk & 1023) * 64;
    int t = threadIdx.x;
    const float* xb = x + (size_t)b * 64 * HWSZ;
    unsigned short* xTb = xT + (size_t)b * HWSZ * 64;
    int pp = t & 63;
    int c0r = t >> 6;
#pragma unroll
    for (int i = 0; i < 16; ++i) {
        int c = c0r + 4 * i;
        tile[c * 65 + pp] = xb[(size_t)c * HWSZ + p0 + pp];
    }
    __syncthreads();
#pragma unroll
    for (int it = 0; it < 2; ++it) {
        int item = t + it * 256;       // 512 items
        int p = item >> 3;
        int c0 = (item & 7) * 8;
        uint4 ow;
        ow.x = f2bf(tile[(c0 + 0) * 65 + p]) | ((unsigned)f2bf(tile[(c0 + 1) * 65 + p]) << 16);
        ow.y = f2bf(tile[(c0 + 2) * 65 + p]) | ((unsigned)f2bf(tile[(c0 + 3) * 65 + p]) << 16);
        ow.z = f2bf(tile[(c0 + 4) * 65 + p]) | ((unsigned)f2bf(tile[(c0 + 5) * 65 + p]) << 16);
        ow.w = f2bf(tile[(c0 + 6) * 65 + p]) | ((unsigned)f2bf(tile[(c0 + 7) * 65 + p]) << 16);
        *(uint4*)&xTb[(size_t)(p0 + p) * 64 + c0] = ow;
    }
}

// ---------------- K1: offset conv via MFMA -> om[b][d][p] ----------------
__global__ __launch_bounds__(256) void offset_conv(const unsigned short* __restrict__ xT,
                                                   const unsigned short* __restrict__ wOffPack,
                                                   const float* __restrict__ b_off,
                                                   float* __restrict__ om) {
    __shared__ uint4 haloBuf[800];     // 10x10 cells x 64ch bf16, swizzled
    char* halo = (char*)haloBuf;
    int bid = blockIdx.x;              // 2048
    int blk = ((bid & 7) << 8) | (bid >> 3);   // XCD-chunked swizzle
    int b = blk >> 10;
    int tb = blk & 1023;
    int ty = tb >> 5, tx = tb & 31;
    int h0 = ty * 8, w0 = tx * 8;
    int t = threadIdx.x;
    const char* xbb = (const char*)(xT + (size_t)b * HWSZ * 64);

    for (int i = t; i < 800; i += 256) {
        int cell = i >> 3;
        int c0 = (i & 7) * 8;
        int r = cell / 10, s = cell - r * 10;
        int y = h0 - 1 + r, xx = w0 - 1 + s;
        uint4 v = {0u, 0u, 0u, 0u};
        if (y >= 0 && y < IMGH && xx >= 0 && xx < IMGW)
            v = *(const uint4*)(xbb + ((size_t)(y * IMGW + xx) << 7) + (c0 << 1));
        *(uint4*)(halo + (cell << 7) + (((c0 << 1)) ^ ((cell & 7) << 4))) = v;
    }
    __syncthreads();

    int lane = t & 63;
    int wid = __builtin_amdgcn_readfirstlane(t >> 6);
    int mt = wid & 1;
    int np = wid >> 1;
    f32x4 z = {0.f, 0.f, 0.f, 0.f};
    f32x4 acc[2] = {z, z};
    int lhi = lane >> 4;

    for (int tap = 0; tap < 9; ++tap) {
        const short8* ap = (const short8*)wOffPack;
        short8 a0 = ap[((mt * 9 + tap) * 2 + 0) * 64 + lane];
        short8 a1 = ap[((mt * 9 + tap) * 2 + 1) * 64 + lane];
        int dy = tap / 3, dx = tap - dy * 3;
#pragma unroll
        for (int nn = 0; nn < 2; ++nn) {
            int p = (np * 2 + nn) * 16 + (lane & 15);
            int cell = ((p >> 3) + dy) * 10 + (p & 7) + dx;
            int base = (cell << 7);
            int swz = (cell & 7) << 4;
            short8 b0 = *(const short8*)(halo + base + ((lhi << 4) ^ swz));
            acc[nn] = __builtin_amdgcn_mfma_f32_16x16x32_bf16(a0, b0, acc[nn], 0, 0, 0);
            short8 b1 = *(const short8*)(halo + base + (((4 + lhi) << 4) ^ swz));
            acc[nn] = __builtin_amdgcn_mfma_f32_16x16x32_bf16(a1, b1, acc[nn], 0, 0, 0);
        }
    }
    float* omb = om + (size_t)b * 27 * HWSZ;
#pragma unroll
    for (int nn = 0; nn < 2; ++nn) {
#pragma unroll
        for (int jj = 0; jj < 4; ++jj) {
            int d = mt * 16 + lhi * 4 + jj;
            if (d < 27) {
                int p = (np * 2 + nn) * 16 + (lane & 15);
                int gp = (h0 + (p >> 3)) * IMGW + w0 + (p & 7);
                omb[(size_t)d * HWSZ + gp] = acc[nn][jj] + b_off[d];
            }
        }
    }
}

// ---------------- K2: deformable sample + MFMA einsum + BN-stats (pipelined) ----------------
__global__ __launch_bounds__(256) void dcn_main(const unsigned short* __restrict__ xT,
                                                const float* __restrict__ om,
                                                const unsigned short* __restrict__ wApack,
                                                unsigned short* __restrict__ preout,
                                                float* __restrict__ stats) {
    __shared__ uint4 SpBuf[1024];      // 2 x (64px x 64ch bf16), swizzled
    __shared__ float prmw[9][64][4];
    __shared__ int prmi[9][64][4];
    char* sp = (char*)SpBuf;
    int bid = blockIdx.x;              // 2048
    int blk = ((bid & 7) << 8) | (bid >> 3);   // XCD-chunked swizzle
    int b = blk >> 10;
    int tb = blk & 1023;
    int ty = tb >> 5, tx = tb & 31;
    int h0 = ty * 8, w0 = tx * 8;
    int t = threadIdx.x;
    const char* xbb = (const char*)(xT + (size_t)b * HWSZ * 64);
    const float* omb = om + (size_t)b * 27 * HWSZ;
    int lane = t & 63;
    int wid = __builtin_amdgcn_readfirstlane(t >> 6);
    int lhi = lane >> 4;

    // phase 0: all 9 taps' bilinear params
    for (int i = t; i < 576; i += 256) {
        int tap = i >> 6, p = i & 63;
        int h = h0 + (p >> 3), wc = w0 + (p & 7);
        int gp = h * IMGW + wc;
        float offy = omb[(size_t)tap * HWSZ + gp];
        float offx = omb[(size_t)(tap + 9) * HWSZ + gp];
        float mraw = omb[(size_t)(tap + 18) * HWSZ + gp];
        float m = 1.f / (1.f + __expf(-mraw));
        float pyf = (float)(h + tap / 3 - 1) + offy;
        float pxf = (float)(wc + tap % 3 - 1) + offx;
        float y0f = floorf(pyf), x0f = floorf(pxf);
        float wy = pyf - y0f, wx = pxf - x0f;
        int y0 = (int)y0f, x0 = (int)x0f;
        int y1 = y0 + 1, x1 = x0 + 1;
        float vy0 = (y0 >= 0 && y0 < IMGH) ? 1.f : 0.f;
        float vy1 = (y1 >= 0 && y1 < IMGH) ? 1.f : 0.f;
        float vx0 = (x0 >= 0 && x0 < IMGW) ? 1.f : 0.f;
        float vx1 = (x1 >= 0 && x1 < IMGW) ? 1.f : 0.f;
        int y0c = min(max(y0, 0), IMGH - 1), y1c = min(max(y1, 0), IMGH - 1);
        int x0c = min(max(x0, 0), IMGW - 1), x1c = min(max(x1, 0), IMGW - 1);
        prmw[tap][p][0] = (1.f - wy) * (1.f - wx) * m * vy0 * vx0;
        prmw[tap][p][1] = (1.f - wy) * wx * m * vy0 * vx1;
        prmw[tap][p][2] = wy * (1.f - wx) * m * vy1 * vx0;
        prmw[tap][p][3] = wy * wx * m * vy1 * vx1;
        prmi[tap][p][0] = (y0c * IMGW + x0c) << 7;
        prmi[tap][p][1] = (y0c * IMGW + x1c) << 7;
        prmi[tap][p][2] = (y1c * IMGW + x0c) << 7;
        prmi[tap][p][3] = (y1c * IMGW + x1c) << 7;
    }
    __syncthreads();

    f32x4 z = {0.f, 0.f, 0.f, 0.f};
    f32x4 acc[4] = {z, z, z, z};
    const short8* ap = (const short8*)wApack;

    int p0 = t >> 3;                   // pixel for item 0 (item 1 = p0+32)
    int c0b = (t & 7) << 4;            // byte offset of this thread's 8-ch slice
    uint4 q[2][4];                     // in-flight gathers: [item][corner]

#define PREFETCH(TAP)                                                        \
    {                                                                        \
        _Pragma("unroll")                                                    \
        for (int it = 0; it < 2; ++it) {                                     \
            int p = p0 + it * 32;                                            \
            int4 ip = *(int4*)&prmi[TAP][p][0];                              \
            q[it][0] = *(const uint4*)(xbb + ip.x + c0b);                    \
            q[it][1] = *(const uint4*)(xbb + ip.y + c0b);                    \
            q[it][2] = *(const uint4*)(xbb + ip.z + c0b);                    \
            q[it][3] = *(const uint4*)(xbb + ip.w + c0b);                    \
        }                                                                    \
    }

#define PACK(TAP, DST)                                                       \
    {                                                                        \
        _Pragma("unroll")                                                    \
        for (int it = 0; it < 2; ++it) {                                     \
            int p = p0 + it * 32;                                            \
            float4 wv = *(float4*)&prmw[TAP][p][0];                          \
            float v[8] = {0.f, 0.f, 0.f, 0.f, 0.f, 0.f, 0.f, 0.f};           \
            acc_corner(q[it][0], wv.x, v);                                   \
            acc_corner(q[it][1], wv.y, v);                                   \
            acc_corner(q[it][2], wv.z, v);                                   \
            acc_corner(q[it][3], wv.w, v);                                   \
            uint4 ow;                                                        \
            ow.x = f2bf(v[0]) | ((unsigned)f2bf(v[1]) << 16);                \
            ow.y = f2bf(v[2]) | ((unsigned)f2bf(v[3]) << 16);                \
            ow.z = f2bf(v[4]) | ((unsigned)f2bf(v[5]) << 16);                \
            ow.w = f2bf(v[6]) | ((unsigned)f2bf(v[7]) << 16);                \
            *(uint4*)((DST) + (p << 7) + (c0b ^ ((p & 7) << 4))) = ow;       \
        }                                                                    \
    }

    PREFETCH(0);
#pragma unroll
    for (int tap = 0; tap < 9; ++tap) {
        char* buf = sp + (tap & 1) * 8192;
        PACK(tap, buf);
        if (tap < 8) PREFETCH(tap + 1);
        short8 a0 = ap[((wid * 9 + tap) * 2 + 0) * 64 + lane];
        short8 a1 = ap[((wid * 9 + tap) * 2 + 1) * 64 + lane];
        __syncthreads();
        __builtin_amdgcn_s_setprio(1);
        int swz = (lane & 7) << 4;
#pragma unroll
        for (int n = 0; n < 4; ++n) {
            int rowb = (n * 16 + (lane & 15)) << 7;
            short8 b0 = *(const short8*)(buf + rowb + ((lhi << 4) ^ swz));
            acc[n] = __builtin_amdgcn_mfma_f32_16x16x32_bf16(a0, b0, acc[n], 0, 0, 0);
            short8 b1 = *(const short8*)(buf + rowb + (((4 + lhi) << 4) ^ swz));
            acc[n] = __builtin_amdgcn_mfma_f32_16x16x32_bf16(a1, b1, acc[n], 0, 0, 0);
        }
        __builtin_amdgcn_s_setprio(0);
    }
#undef PREFETCH
#undef PACK

    // epilogue: preout (bf16, NCHW) + fused BN partial stats
    unsigned short* pob = preout + (size_t)b * 64 * HWSZ;
#pragma unroll
    for (int n = 0; n < 4; ++n) {
#pragma unroll
        for (int jj = 0; jj < 4; ++jj) {
            int o = wid * 16 + lhi * 4 + jj;
            int p = n * 16 + (lane & 15);
            int gp = (h0 + (p >> 3)) * IMGW + w0 + (p & 7);
            pob[(size_t)o * HWSZ + gp] = f2bf(acc[n][jj]);
        }
    }
#pragma unroll
    for (int jj = 0; jj < 4; ++jj) {
        float s1 = acc[0][jj] + acc[1][jj] + acc[2][jj] + acc[3][jj];
        float s2 = acc[0][jj] * acc[0][jj] + acc[1][jj] * acc[1][jj]
                 + acc[2][jj] * acc[2][jj] + acc[3][jj] * acc[3][jj];
#pragma unroll
        for (int mask = 1; mask < 16; mask <<= 1) {
            s1 += __shfl_xor(s1, mask);
            s2 += __shfl_xor(s2, mask);
        }
        if ((lane & 15) == 0) {
            int o = wid * 16 + lhi * 4 + jj;
            atomicAdd(&stats[o], s1);
            atomicAdd(&stats[64 + o], s2);
        }
    }
}

// ---------------- K3: normalize + relu + residual ----------------
__global__ __launch_bounds__(256) void bn_finalize(const float* __restrict__ stats,
                                                   const float* __restrict__ gamma,
                                                   const float* __restrict__ beta,
                                                   const float* __restrict__ x,
                                                   const unsigned short* __restrict__ preout,
                                                   float* __restrict__ out) {
    int i = blockIdx.x * 256 + threadIdx.x;     // uint4 idx over 8.4M bf16
    int e0 = i * 8;
    int o = (e0 >> 16) & 63;
    const float inv_n = 1.f / 131072.f;
    float mean = stats[o] * inv_n;
    float var = stats[64 + o] * inv_n - mean * mean;
    float rstd = rsqrtf(var + 1e-5f);
    float g = gamma[o] * rstd;
    float bb = beta[o] - mean * g;
    uint4 q = ((const uint4*)preout)[i];
    float4 x0 = ((const float4*)x)[i * 2];
    float4 x1 = ((const float4*)x)[i * 2 + 1];
    float4 r0, r1;
    r0.x = fmaxf(__uint_as_float(q.x << 16) * g + bb, 0.f) + x0.x;
    r0.y = fmaxf(__uint_as_float(q.x & 0xffff0000u) * g + bb, 0.f) + x0.y;
    r0.z = fmaxf(__uint_as_float(q.y << 16) * g + bb, 0.f) + x0.z;
    r0.w = fmaxf(__uint_as_float(q.y & 0xffff0000u) * g + bb, 0.f) + x0.w;
    r1.x = fmaxf(__uint_as_float(q.z << 16) * g + bb, 0.f) + x1.x;
    r1.y = fmaxf(__uint_as_float(q.z & 0xffff0000u) * g + bb, 0.f) + x1.y;
    r1.z = fmaxf(__uint_as_float(q.w << 16) * g + bb, 0.f) + x1.z;
    r1.w = fmaxf(__uint_as_float(q.w & 0xffff0000u) * g + bb, 0.f) + x1.w;
    ((float4*)out)[i * 2] = r0;
    ((float4*)out)[i * 2 + 1] = r1;
}

extern "C" void kernel_launch(void* const* d_in, const int* in_sizes, int n_in,
                              void* d_out, int out_size, void* d_ws, size_t ws_size,
                              hipStream_t stream) {
    const float* x     = (const float*)d_in[0];
    const float* w_off = (const float*)d_in[1];
    const float* b_off = (const float*)d_in[2];
    const float* w     = (const float*)d_in[3];
    const float* gamma = (const float*)d_in[5];
    const float* beta  = (const float*)d_in[6];
    float* out = (float*)d_out;
    char* wsb = (char*)d_ws;

    unsigned short* xT       = (unsigned short*)wsb;                    // 16,777,216 B
    float*          om       = (float*)(wsb + 16777216);                // 14,155,776 B
    unsigned short* preout   = (unsigned short*)(wsb + 30932992);       // 16,777,216 B
    unsigned short* wApack   = (unsigned short*)(wsb + 47710208);       // 73,728 B
    unsigned short* wOffPack = (unsigned short*)(wsb + 47783936);       // 36,864 B
    float*          stats    = (float*)(wsb + 47820800);                // 512 B

    hipMemsetAsync(stats, 0, 512, stream);
    prep_weights<<<216, 256, 0, stream>>>(w_off, w, wApack, wOffPack);
    transpose_x<<<2048, 256, 0, stream>>>(x, xT);
    offset_conv<<<2048, 256, 0, stream>>>(xT, wOffPack, b_off, om);
    dcn_main<<<2048, 256, 0, stream>>>(xT, om, wApack, preout, stats);
    bn_finalize<<<4096, 256, 0, stream>>>(stats, gamma, beta, x, preout, out);
}

// Round 4
// 171.708 us; speedup vs baseline: 2.5669x; 1.5119x over previous
//
#include <hip/hip_runtime.h>
#include <math.h>

#define HWSZ 65536   // 256*256
#define IMGH 256
#define IMGW 256

typedef short short8 __attribute__((ext_vector_type(8)));
typedef float f32x4 __attribute__((ext_vector_type(4)));

__device__ inline unsigned short f2bf(float f) {
    unsigned u = __float_as_uint(f);
    return (unsigned short)((u + 0x7fffu + ((u >> 16) & 1u)) >> 16);
}

__device__ inline void acc_corner(const uint4 q, float w, float* v) {
    v[0] += w * __uint_as_float(q.x << 16);
    v[1] += w * __uint_as_float(q.x & 0xffff0000u);
    v[2] += w * __uint_as_float(q.y << 16);
    v[3] += w * __uint_as_float(q.y & 0xffff0000u);
    v[4] += w * __uint_as_float(q.z << 16);
    v[5] += w * __uint_as_float(q.z & 0xffff0000u);
    v[6] += w * __uint_as_float(q.w << 16);
    v[7] += w * __uint_as_float(q.w & 0xffff0000u);
}

__device__ inline short8 pack8(const float* v) {
    union { unsigned u[4]; short8 s; } r;
    r.u[0] = f2bf(v[0]) | ((unsigned)f2bf(v[1]) << 16);
    r.u[1] = f2bf(v[2]) | ((unsigned)f2bf(v[3]) << 16);
    r.u[2] = f2bf(v[4]) | ((unsigned)f2bf(v[5]) << 16);
    r.u[3] = f2bf(v[6]) | ((unsigned)f2bf(v[7]) << 16);
    return r.s;
}

// ---------------- K0a: pack MFMA A-fragments (bf16) ----------------
__global__ void prep_weights(const float* __restrict__ w_off,
                             const float* __restrict__ w,
                             unsigned short* __restrict__ wApack,
                             unsigned short* __restrict__ wOffPack) {
    int i = blockIdx.x * 256 + threadIdx.x;
    if (i < 36864) {
        int e = i;
        int j = e & 7, lane = (e >> 3) & 63, kk = (e >> 9) & 1;
        int t2 = e >> 10;
        int tap = t2 % 9, g = t2 / 9;
        int o = g * 16 + (lane & 15);
        int c = kk * 32 + ((lane >> 4) & 3) * 8 + j;
        wApack[e] = f2bf(w[(o * 64 + c) * 9 + tap]);
    } else if (i < 36864 + 18432) {
        int e = i - 36864;
        int j = e & 7, lane = (e >> 3) & 63, kk = (e >> 9) & 1;
        int t2 = e >> 10;
        int tap = t2 % 9, mt = t2 / 9;
        int d = mt * 16 + (lane & 15);
        int c = kk * 32 + ((lane >> 4) & 3) * 8 + j;
        float v = (d < 27) ? w_off[(d * 64 + c) * 9 + tap] : 0.f;
        wOffPack[e] = f2bf(v);
    }
}

// ---------------- K0b: x NCHW fp32 -> NHWC bf16 ----------------
__global__ __launch_bounds__(256) void transpose_x(const float* __restrict__ x,
                                                   unsigned short* __restrict__ xT) {
    __shared__ float tile[64 * 65];
    int blk = blockIdx.x;              // 2048 = 2 * 1024
    int b = blk >> 10;
    int p0 = (blk & 1023) * 64;
    int t = threadIdx.x;
    const float* xb = x + (size_t)b * 64 * HWSZ;
    unsigned short* xTb = xT + (size_t)b * HWSZ * 64;
    int pp = t & 63;
    int c0r = t >> 6;
#pragma unroll
    for (int i = 0; i < 16; ++i) {
        int c = c0r + 4 * i;
        tile[c * 65 + pp] = xb[(size_t)c * HWSZ + p0 + pp];
    }
    __syncthreads();
#pragma unroll
    for (int it = 0; it < 2; ++it) {
        int item = t + it * 256;       // 512 items
        int p = item >> 3;
        int c0 = (item & 7) * 8;
        uint4 ow;
        ow.x = f2bf(tile[(c0 + 0) * 65 + p]) | ((unsigned)f2bf(tile[(c0 + 1) * 65 + p]) << 16);
        ow.y = f2bf(tile[(c0 + 2) * 65 + p]) | ((unsigned)f2bf(tile[(c0 + 3) * 65 + p]) << 16);
        ow.z = f2bf(tile[(c0 + 4) * 65 + p]) | ((unsigned)f2bf(tile[(c0 + 5) * 65 + p]) << 16);
        ow.w = f2bf(tile[(c0 + 6) * 65 + p]) | ((unsigned)f2bf(tile[(c0 + 7) * 65 + p]) << 16);
        *(uint4*)&xTb[(size_t)(p0 + p) * 64 + c0] = ow;
    }
}

// ---------------- K1: offset conv via MFMA -> om[b][d][p] ----------------
__global__ __launch_bounds__(256) void offset_conv(const unsigned short* __restrict__ xT,
                                                   const unsigned short* __restrict__ wOffPack,
                                                   const float* __restrict__ b_off,
                                                   float* __restrict__ om) {
    __shared__ uint4 haloBuf[800];     // 10x10 cells x 64ch bf16, swizzled
    char* halo = (char*)haloBuf;
    int bid = blockIdx.x;              // 2048
    int blk = ((bid & 7) << 8) | (bid >> 3);   // XCD-chunked swizzle
    int b = blk >> 10;
    int tb = blk & 1023;
    int ty = tb >> 5, tx = tb & 31;
    int h0 = ty * 8, w0 = tx * 8;
    int t = threadIdx.x;
    const char* xbb = (const char*)(xT + (size_t)b * HWSZ * 64);

    for (int i = t; i < 800; i += 256) {
        int cell = i >> 3;
        int c0 = (i & 7) * 8;
        int r = cell / 10, s = cell - r * 10;
        int y = h0 - 1 + r, xx = w0 - 1 + s;
        uint4 v = {0u, 0u, 0u, 0u};
        if (y >= 0 && y < IMGH && xx >= 0 && xx < IMGW)
            v = *(const uint4*)(xbb + ((size_t)(y * IMGW + xx) << 7) + (c0 << 1));
        *(uint4*)(halo + (cell << 7) + (((c0 << 1)) ^ ((cell & 7) << 4))) = v;
    }
    __syncthreads();

    int lane = t & 63;
    int wid = __builtin_amdgcn_readfirstlane(t >> 6);
    int mt = wid & 1;
    int np = wid >> 1;
    f32x4 z = {0.f, 0.f, 0.f, 0.f};
    f32x4 acc[2] = {z, z};
    int lhi = lane >> 4;

    for (int tap = 0; tap < 9; ++tap) {
        const short8* ap = (const short8*)wOffPack;
        short8 a0 = ap[((mt * 9 + tap) * 2 + 0) * 64 + lane];
        short8 a1 = ap[((mt * 9 + tap) * 2 + 1) * 64 + lane];
        int dy = tap / 3, dx = tap - dy * 3;
#pragma unroll
        for (int nn = 0; nn < 2; ++nn) {
            int p = (np * 2 + nn) * 16 + (lane & 15);
            int cell = ((p >> 3) + dy) * 10 + (p & 7) + dx;
            int base = (cell << 7);
            int swz = (cell & 7) << 4;
            short8 b0 = *(const short8*)(halo + base + ((lhi << 4) ^ swz));
            acc[nn] = __builtin_amdgcn_mfma_f32_16x16x32_bf16(a0, b0, acc[nn], 0, 0, 0);
            short8 b1 = *(const short8*)(halo + base + (((4 + lhi) << 4) ^ swz));
            acc[nn] = __builtin_amdgcn_mfma_f32_16x16x32_bf16(a1, b1, acc[nn], 0, 0, 0);
        }
    }
    float* omb = om + (size_t)b * 27 * HWSZ;
#pragma unroll
    for (int nn = 0; nn < 2; ++nn) {
#pragma unroll
        for (int jj = 0; jj < 4; ++jj) {
            int d = mt * 16 + lhi * 4 + jj;
            if (d < 27) {
                int p = (np * 2 + nn) * 16 + (lane & 15);
                int gp = (h0 + (p >> 3)) * IMGW + w0 + (p & 7);
                omb[(size_t)d * HWSZ + gp] = acc[nn][jj] + b_off[d];
            }
        }
    }
}

// ---------------- K2: wave-independent deformable sample + MFMA einsum ----------------
// wave = 16 pixels (one n-tile) x all 64 out-channels. B-fragment built fully
// in registers (thread gathers exactly its own slice). NO barriers in main loop.
__global__ __launch_bounds__(256, 4) void dcn_main(const unsigned short* __restrict__ xT,
                                                   const float* __restrict__ om,
                                                   const unsigned short* __restrict__ wApack,
                                                   unsigned short* __restrict__ preout,
                                                   float* __restrict__ stats) {
    __shared__ float prmw[9][64][4];
    __shared__ int prmi[9][64][4];
    __shared__ float bstats[128];
    int bid = blockIdx.x;              // 2048
    int blk = ((bid & 7) << 8) | (bid >> 3);   // XCD-chunked swizzle
    int b = blk >> 10;
    int tb = blk & 1023;
    int ty = tb >> 5, tx = tb & 31;
    int h0 = ty * 8, w0 = tx * 8;
    int t = threadIdx.x;
    const char* xbb = (const char*)(xT + (size_t)b * HWSZ * 64);
    const float* omb = om + (size_t)b * 27 * HWSZ;
    int lane = t & 63;
    int wid = t >> 6;                  // wave id = n-tile (pixel group)
    int lp = lane & 15;                // pixel within tile
    int lhi = lane >> 4;               // k-quarter
    int p = wid * 16 + lp;             // pixel 0..63 in 8x8 tile

    if (t < 128) bstats[t] = 0.f;

    // phase 0: all 9 taps' bilinear params (cooperative; ONE barrier total)
    for (int i = t; i < 576; i += 256) {
        int tap = i >> 6, pp = i & 63;
        int h = h0 + (pp >> 3), wc = w0 + (pp & 7);
        int gp = h * IMGW + wc;
        float offy = omb[(size_t)tap * HWSZ + gp];
        float offx = omb[(size_t)(tap + 9) * HWSZ + gp];
        float mraw = omb[(size_t)(tap + 18) * HWSZ + gp];
        float m = 1.f / (1.f + __expf(-mraw));
        float pyf = (float)(h + tap / 3 - 1) + offy;
        float pxf = (float)(wc + tap % 3 - 1) + offx;
        float y0f = floorf(pyf), x0f = floorf(pxf);
        float wy = pyf - y0f, wx = pxf - x0f;
        int y0 = (int)y0f, x0 = (int)x0f;
        int y1 = y0 + 1, x1 = x0 + 1;
        float vy0 = (y0 >= 0 && y0 < IMGH) ? 1.f : 0.f;
        float vy1 = (y1 >= 0 && y1 < IMGH) ? 1.f : 0.f;
        float vx0 = (x0 >= 0 && x0 < IMGW) ? 1.f : 0.f;
        float vx1 = (x1 >= 0 && x1 < IMGW) ? 1.f : 0.f;
        int y0c = min(max(y0, 0), IMGH - 1), y1c = min(max(y1, 0), IMGH - 1);
        int x0c = min(max(x0, 0), IMGW - 1), x1c = min(max(x1, 0), IMGW - 1);
        prmw[tap][pp][0] = (1.f - wy) * (1.f - wx) * m * vy0 * vx0;
        prmw[tap][pp][1] = (1.f - wy) * wx * m * vy0 * vx1;
        prmw[tap][pp][2] = wy * (1.f - wx) * m * vy1 * vx0;
        prmw[tap][pp][3] = wy * wx * m * vy1 * vx1;
        prmi[tap][pp][0] = (y0c * IMGW + x0c) << 7;
        prmi[tap][pp][1] = (y0c * IMGW + x1c) << 7;
        prmi[tap][pp][2] = (y1c * IMGW + x0c) << 7;
        prmi[tap][pp][3] = (y1c * IMGW + x1c) << 7;
    }
    __syncthreads();
    // ---- from here: waves fully independent, zero barriers ----

    f32x4 z = {0.f, 0.f, 0.f, 0.f};
    f32x4 acc[4] = {z, z, z, z};
    const short8* ap = (const short8*)wApack;
    int coff = lhi << 4;               // byte offset of this thread's 8-ch slice

    uint4 q[4][2];                     // in-flight gathers [corner][kk]
#define PREFETCH(TAP)                                                         \
    {                                                                         \
        int4 ip = *(int4*)&prmi[TAP][p][0];                                   \
        q[0][0] = *(const uint4*)(xbb + ip.x + coff);                         \
        q[0][1] = *(const uint4*)(xbb + ip.x + 64 + coff);                    \
        q[1][0] = *(const uint4*)(xbb + ip.y + coff);                         \
        q[1][1] = *(const uint4*)(xbb + ip.y + 64 + coff);                    \
        q[2][0] = *(const uint4*)(xbb + ip.z + coff);                         \
        q[2][1] = *(const uint4*)(xbb + ip.z + 64 + coff);                    \
        q[3][0] = *(const uint4*)(xbb + ip.w + coff);                         \
        q[3][1] = *(const uint4*)(xbb + ip.w + 64 + coff);                    \
    }

    PREFETCH(0);
#pragma unroll
    for (int tap = 0; tap < 9; ++tap) {
        float4 wv = *(float4*)&prmw[tap][p][0];
        float v0[8] = {0.f, 0.f, 0.f, 0.f, 0.f, 0.f, 0.f, 0.f};
        float v1[8] = {0.f, 0.f, 0.f, 0.f, 0.f, 0.f, 0.f, 0.f};
        acc_corner(q[0][0], wv.x, v0);
        acc_corner(q[0][1], wv.x, v1);
        acc_corner(q[1][0], wv.y, v0);
        acc_corner(q[1][1], wv.y, v1);
        acc_corner(q[2][0], wv.z, v0);
        acc_corner(q[2][1], wv.z, v1);
        acc_corner(q[3][0], wv.w, v0);
        acc_corner(q[3][1], wv.w, v1);
        short8 b0 = pack8(v0);
        short8 b1 = pack8(v1);
        if (tap < 8) PREFETCH(tap + 1);
#pragma unroll
        for (int g = 0; g < 4; ++g) {
            short8 a0 = ap[((g * 9 + tap) * 2 + 0) * 64 + lane];
            short8 a1 = ap[((g * 9 + tap) * 2 + 1) * 64 + lane];
            acc[g] = __builtin_amdgcn_mfma_f32_16x16x32_bf16(a0, b0, acc[g], 0, 0, 0);
            acc[g] = __builtin_amdgcn_mfma_f32_16x16x32_bf16(a1, b1, acc[g], 0, 0, 0);
        }
    }
#undef PREFETCH

    // epilogue: preout (bf16, NCHW), pixel = wave's tile, lane&15
    unsigned short* pob = preout + (size_t)b * 64 * HWSZ;
    int gp = (h0 + (p >> 3)) * IMGW + w0 + (p & 7);
#pragma unroll
    for (int g = 0; g < 4; ++g) {
#pragma unroll
        for (int jj = 0; jj < 4; ++jj) {
            int o = g * 16 + lhi * 4 + jj;
            pob[(size_t)o * HWSZ + gp] = f2bf(acc[g][jj]);
        }
    }
    // BN partial stats: reduce over the 16 pixels (lanes lp=0..15), LDS-accumulate
#pragma unroll
    for (int g = 0; g < 4; ++g) {
#pragma unroll
        for (int jj = 0; jj < 4; ++jj) {
            float s1 = acc[g][jj];
            float s2 = s1 * s1;
#pragma unroll
            for (int mask = 1; mask < 16; mask <<= 1) {
                s1 += __shfl_xor(s1, mask);
                s2 += __shfl_xor(s2, mask);
            }
            if (lp == 0) {
                int o = g * 16 + lhi * 4 + jj;
                atomicAdd(&bstats[o], s1);
                atomicAdd(&bstats[64 + o], s2);
            }
        }
    }
    __syncthreads();
    if (t < 128) atomicAdd(&stats[t], bstats[t]);
}

// ---------------- K3: normalize + relu + residual ----------------
__global__ __launch_bounds__(256) void bn_finalize(const float* __restrict__ stats,
                                                   const float* __restrict__ gamma,
                                                   const float* __restrict__ beta,
                                                   const float* __restrict__ x,
                                                   const unsigned short* __restrict__ preout,
                                                   float* __restrict__ out) {
    int i = blockIdx.x * 256 + threadIdx.x;     // uint4 idx over 8.4M bf16
    int e0 = i * 8;
    int o = (e0 >> 16) & 63;
    const float inv_n = 1.f / 131072.f;
    float mean = stats[o] * inv_n;
    float var = stats[64 + o] * inv_n - mean * mean;
    float rstd = rsqrtf(var + 1e-5f);
    float g = gamma[o] * rstd;
    float bb = beta[o] - mean * g;
    uint4 q = ((const uint4*)preout)[i];
    float4 x0 = ((const float4*)x)[i * 2];
    float4 x1 = ((const float4*)x)[i * 2 + 1];
    float4 r0, r1;
    r0.x = fmaxf(__uint_as_float(q.x << 16) * g + bb, 0.f) + x0.x;
    r0.y = fmaxf(__uint_as_float(q.x & 0xffff0000u) * g + bb, 0.f) + x0.y;
    r0.z = fmaxf(__uint_as_float(q.y << 16) * g + bb, 0.f) + x0.z;
    r0.w = fmaxf(__uint_as_float(q.y & 0xffff0000u) * g + bb, 0.f) + x0.w;
    r1.x = fmaxf(__uint_as_float(q.z << 16) * g + bb, 0.f) + x1.x;
    r1.y = fmaxf(__uint_as_float(q.z & 0xffff0000u) * g + bb, 0.f) + x1.y;
    r1.z = fmaxf(__uint_as_float(q.w << 16) * g + bb, 0.f) + x1.z;
    r1.w = fmaxf(__uint_as_float(q.w & 0xffff0000u) * g + bb, 0.f) + x1.w;
    ((float4*)out)[i * 2] = r0;
    ((float4*)out)[i * 2 + 1] = r1;
}

extern "C" void kernel_launch(void* const* d_in, const int* in_sizes, int n_in,
                              void* d_out, int out_size, void* d_ws, size_t ws_size,
                              hipStream_t stream) {
    const float* x     = (const float*)d_in[0];
    const float* w_off = (const float*)d_in[1];
    const float* b_off = (const float*)d_in[2];
    const float* w     = (const float*)d_in[3];
    const float* gamma = (const float*)d_in[5];
    const float* beta  = (const float*)d_in[6];
    float* out = (float*)d_out;
    char* wsb = (char*)d_ws;

    unsigned short* xT       = (unsigned short*)wsb;                    // 16,777,216 B
    float*          om       = (float*)(wsb + 16777216);                // 14,155,776 B
    unsigned short* preout   = (unsigned short*)(wsb + 30932992);       // 16,777,216 B
    unsigned short* wApack   = (unsigned short*)(wsb + 47710208);       // 73,728 B
    unsigned short* wOffPack = (unsigned short*)(wsb + 47783936);       // 36,864 B
    float*          stats    = (float*)(wsb + 47820800);                // 512 B

    hipMemsetAsync(stats, 0, 512, stream);
    prep_weights<<<216, 256, 0, stream>>>(w_off, w, wApack, wOffPack);
    transpose_x<<<2048, 256, 0, stream>>>(x, xT);
    offset_conv<<<2048, 256, 0, stream>>>(xT, wOffPack, b_off, om);
    dcn_main<<<2048, 256, 0, stream>>>(xT, om, wApack, preout, stats);
    bn_finalize<<<4096, 256, 0, stream>>>(stats, gamma, beta, x, preout, out);
}

// Round 5
// 136.623 us; speedup vs baseline: 3.2261x; 1.2568x over previous
//
#include <hip/hip_runtime.h>
#include <math.h>

#define HWSZ 65536   // 256*256
#define IMGH 256
#define IMGW 256

typedef short short8 __attribute__((ext_vector_type(8)));
typedef float f32x4 __attribute__((ext_vector_type(4)));

__device__ inline unsigned short f2bf(float f) {
    unsigned u = __float_as_uint(f);
    return (unsigned short)((u + 0x7fffu + ((u >> 16) & 1u)) >> 16);
}

__device__ inline void acc_corner(const uint4 q, float w, float* v) {
    v[0] += w * __uint_as_float(q.x << 16);
    v[1] += w * __uint_as_float(q.x & 0xffff0000u);
    v[2] += w * __uint_as_float(q.y << 16);
    v[3] += w * __uint_as_float(q.y & 0xffff0000u);
    v[4] += w * __uint_as_float(q.z << 16);
    v[5] += w * __uint_as_float(q.z & 0xffff0000u);
    v[6] += w * __uint_as_float(q.w << 16);
    v[7] += w * __uint_as_float(q.w & 0xffff0000u);
}

__device__ inline short8 pack8(const float* v) {
    union { unsigned u[4]; short8 s; } r;
    r.u[0] = f2bf(v[0]) | ((unsigned)f2bf(v[1]) << 16);
    r.u[1] = f2bf(v[2]) | ((unsigned)f2bf(v[3]) << 16);
    r.u[2] = f2bf(v[4]) | ((unsigned)f2bf(v[5]) << 16);
    r.u[3] = f2bf(v[6]) | ((unsigned)f2bf(v[7]) << 16);
    return r.s;
}

// ---------------- K0a: pack MFMA A-fragments (bf16) ----------------
__global__ void prep_weights(const float* __restrict__ w_off,
                             const float* __restrict__ w,
                             unsigned short* __restrict__ wApack,
                             unsigned short* __restrict__ wOffPack) {
    int i = blockIdx.x * 256 + threadIdx.x;
    if (i < 36864) {
        int e = i;
        int j = e & 7, lane = (e >> 3) & 63, kk = (e >> 9) & 1;
        int t2 = e >> 10;
        int tap = t2 % 9, g = t2 / 9;
        int o = g * 16 + (lane & 15);
        int c = kk * 32 + ((lane >> 4) & 3) * 8 + j;
        wApack[e] = f2bf(w[(o * 64 + c) * 9 + tap]);
    } else if (i < 36864 + 18432) {
        int e = i - 36864;
        int j = e & 7, lane = (e >> 3) & 63, kk = (e >> 9) & 1;
        int t2 = e >> 10;
        int tap = t2 % 9, mt = t2 / 9;
        int d = mt * 16 + (lane & 15);
        int c = kk * 32 + ((lane >> 4) & 3) * 8 + j;
        float v = (d < 27) ? w_off[(d * 64 + c) * 9 + tap] : 0.f;
        wOffPack[e] = f2bf(v);
    }
}

// ---------------- K0b: x NCHW fp32 -> NHWC bf16 ----------------
__global__ __launch_bounds__(256) void transpose_x(const float* __restrict__ x,
                                                   unsigned short* __restrict__ xT) {
    __shared__ float tile[64 * 65];
    int blk = blockIdx.x;              // 2048 = 2 * 1024
    int b = blk >> 10;
    int p0 = (blk & 1023) * 64;
    int t = threadIdx.x;
    const float* xb = x + (size_t)b * 64 * HWSZ;
    unsigned short* xTb = xT + (size_t)b * HWSZ * 64;
    int pp = t & 63;
    int c0r = t >> 6;
#pragma unroll
    for (int i = 0; i < 16; ++i) {
        int c = c0r + 4 * i;
        tile[c * 65 + pp] = xb[(size_t)c * HWSZ + p0 + pp];
    }
    __syncthreads();
#pragma unroll
    for (int it = 0; it < 2; ++it) {
        int item = t + it * 256;       // 512 items
        int p = item >> 3;
        int c0 = (item & 7) * 8;
        uint4 ow;
        ow.x = f2bf(tile[(c0 + 0) * 65 + p]) | ((unsigned)f2bf(tile[(c0 + 1) * 65 + p]) << 16);
        ow.y = f2bf(tile[(c0 + 2) * 65 + p]) | ((unsigned)f2bf(tile[(c0 + 3) * 65 + p]) << 16);
        ow.z = f2bf(tile[(c0 + 4) * 65 + p]) | ((unsigned)f2bf(tile[(c0 + 5) * 65 + p]) << 16);
        ow.w = f2bf(tile[(c0 + 6) * 65 + p]) | ((unsigned)f2bf(tile[(c0 + 7) * 65 + p]) << 16);
        *(uint4*)&xTb[(size_t)(p0 + p) * 64 + c0] = ow;
    }
}

// ---------------- K1: offset conv via MFMA -> om[b][d][p] ----------------
__global__ __launch_bounds__(256) void offset_conv(const unsigned short* __restrict__ xT,
                                                   const unsigned short* __restrict__ wOffPack,
                                                   const float* __restrict__ b_off,
                                                   float* __restrict__ om) {
    __shared__ uint4 haloBuf[800];     // 10x10 cells x 64ch bf16, swizzled
    char* halo = (char*)haloBuf;
    int bid = blockIdx.x;              // 2048
    int blk = ((bid & 7) << 8) | (bid >> 3);   // XCD-chunked swizzle
    int b = blk >> 10;
    int tb = blk & 1023;
    int ty = tb >> 5, tx = tb & 31;
    int h0 = ty * 8, w0 = tx * 8;
    int t = threadIdx.x;
    const char* xbb = (const char*)(xT + (size_t)b * HWSZ * 64);

    for (int i = t; i < 800; i += 256) {
        int cell = i >> 3;
        int c0 = (i & 7) * 8;
        int r = cell / 10, s = cell - r * 10;
        int y = h0 - 1 + r, xx = w0 - 1 + s;
        uint4 v = {0u, 0u, 0u, 0u};
        if (y >= 0 && y < IMGH && xx >= 0 && xx < IMGW)
            v = *(const uint4*)(xbb + ((size_t)(y * IMGW + xx) << 7) + (c0 << 1));
        *(uint4*)(halo + (cell << 7) + (((c0 << 1)) ^ ((cell & 7) << 4))) = v;
    }
    __syncthreads();

    int lane = t & 63;
    int wid = __builtin_amdgcn_readfirstlane(t >> 6);
    int mt = wid & 1;
    int np = wid >> 1;
    f32x4 z = {0.f, 0.f, 0.f, 0.f};
    f32x4 acc[2] = {z, z};
    int lhi = lane >> 4;

    for (int tap = 0; tap < 9; ++tap) {
        const short8* ap = (const short8*)wOffPack;
        short8 a0 = ap[((mt * 9 + tap) * 2 + 0) * 64 + lane];
        short8 a1 = ap[((mt * 9 + tap) * 2 + 1) * 64 + lane];
        int dy = tap / 3, dx = tap - dy * 3;
#pragma unroll
        for (int nn = 0; nn < 2; ++nn) {
            int p = (np * 2 + nn) * 16 + (lane & 15);
            int cell = ((p >> 3) + dy) * 10 + (p & 7) + dx;
            int base = (cell << 7);
            int swz = (cell & 7) << 4;
            short8 b0 = *(const short8*)(halo + base + ((lhi << 4) ^ swz));
            acc[nn] = __builtin_amdgcn_mfma_f32_16x16x32_bf16(a0, b0, acc[nn], 0, 0, 0);
            short8 b1 = *(const short8*)(halo + base + (((4 + lhi) << 4) ^ swz));
            acc[nn] = __builtin_amdgcn_mfma_f32_16x16x32_bf16(a1, b1, acc[nn], 0, 0, 0);
        }
    }
    float* omb = om + (size_t)b * 27 * HWSZ;
#pragma unroll
    for (int nn = 0; nn < 2; ++nn) {
#pragma unroll
        for (int jj = 0; jj < 4; ++jj) {
            int d = mt * 16 + lhi * 4 + jj;
            if (d < 27) {
                int p = (np * 2 + nn) * 16 + (lane & 15);
                int gp = (h0 + (p >> 3)) * IMGW + w0 + (p & 7);
                omb[(size_t)d * HWSZ + gp] = acc[nn][jj] + b_off[d];
            }
        }
    }
}

// ---------------- K2: LDS-halo deformable sample + MFMA einsum ----------------
// Halo = 20x20 px x 64ch bf16 (rows h0-5..h0+14), chunk-XOR swizzled. Gathers
// are ds_read_b128; out-of-halo corners (rare) take ballot-guarded global path.
__global__ __launch_bounds__(256, 2) void dcn_main(const unsigned short* __restrict__ xT,
                                                   const float* __restrict__ om,
                                                   const unsigned short* __restrict__ wApack,
                                                   unsigned short* __restrict__ preout,
                                                   float* __restrict__ stats) {
    __shared__ uint4 haloBuf[3200];    // 51.2 KB
    __shared__ float prmw[9][64][4];   // 9.2 KB
    __shared__ int prmi[9][64][4];     // 9.2 KB
    __shared__ float bstats[128];
    char* halo = (char*)haloBuf;
    int bid = blockIdx.x;              // 2048
    int blk = ((bid & 7) << 8) | (bid >> 3);   // XCD-chunked swizzle
    int b = blk >> 10;
    int tb = blk & 1023;
    int ty = tb >> 5, tx = tb & 31;
    int h0 = ty * 8, w0 = tx * 8;
    int t = threadIdx.x;
    const char* xbb = (const char*)(xT + (size_t)b * HWSZ * 64);
    const float* omb = om + (size_t)b * 27 * HWSZ;
    int lane = t & 63;
    int wid = t >> 6;
    int lp = lane & 15;
    int lhi = lane >> 4;
    int p = wid * 16 + lp;
    int hb = h0 - 5, wb = w0 - 5;

    if (t < 128) bstats[t] = 0.f;

    // stage halo: 400 cells x 128B, chunk ch stored at slot ch^(cell&7)
    for (int i = t; i < 3200; i += 256) {
        int cell = i >> 3;
        int ch = i & 7;
        int r = cell / 20, c = cell - r * 20;
        int y = hb + r, xx = wb + c;
        uint4 v = {0u, 0u, 0u, 0u};
        if ((unsigned)y < 256u && (unsigned)xx < 256u)
            v = *(const uint4*)(xbb + ((size_t)((y << 8) + xx) << 7) + (ch << 4));
        *(uint4*)(halo + (cell << 7) + ((ch ^ (cell & 7)) << 4)) = v;
    }

    // bilinear params for all 9 taps; prmi tagged: bit0=1 -> global fallback
    for (int i = t; i < 576; i += 256) {
        int tap = i >> 6, pp = i & 63;
        int h = h0 + (pp >> 3), wc = w0 + (pp & 7);
        int gp = h * IMGW + wc;
        float offy = omb[(size_t)tap * HWSZ + gp];
        float offx = omb[(size_t)(tap + 9) * HWSZ + gp];
        float mraw = omb[(size_t)(tap + 18) * HWSZ + gp];
        float m = 1.f / (1.f + __expf(-mraw));
        float pyf = (float)(h + tap / 3 - 1) + offy;
        float pxf = (float)(wc + tap % 3 - 1) + offx;
        float y0f = floorf(pyf), x0f = floorf(pxf);
        float wy = pyf - y0f, wx = pxf - x0f;
        int y0 = (int)y0f, x0 = (int)x0f;
        int y1 = y0 + 1, x1 = x0 + 1;
        float vy0 = (y0 >= 0 && y0 < IMGH) ? 1.f : 0.f;
        float vy1 = (y1 >= 0 && y1 < IMGH) ? 1.f : 0.f;
        float vx0 = (x0 >= 0 && x0 < IMGW) ? 1.f : 0.f;
        float vx1 = (x1 >= 0 && x1 < IMGW) ? 1.f : 0.f;
        int y0c = min(max(y0, 0), IMGH - 1), y1c = min(max(y1, 0), IMGH - 1);
        int x0c = min(max(x0, 0), IMGW - 1), x1c = min(max(x1, 0), IMGW - 1);
        prmw[tap][pp][0] = (1.f - wy) * (1.f - wx) * m * vy0 * vx0;
        prmw[tap][pp][1] = (1.f - wy) * wx * m * vy0 * vx1;
        prmw[tap][pp][2] = wy * (1.f - wx) * m * vy1 * vx0;
        prmw[tap][pp][3] = wy * wx * m * vy1 * vx1;
        int ry0 = y0c - hb, ry1 = y1c - hb;
        int rx0 = x0c - wb, rx1 = x1c - wb;
        bool iy0 = (unsigned)ry0 < 20u, iy1 = (unsigned)ry1 < 20u;
        bool ix0 = (unsigned)rx0 < 20u, ix1 = (unsigned)rx1 < 20u;
        prmi[tap][pp][0] = (iy0 && ix0) ? ((ry0 * 20 + rx0) << 7) : ((((y0c << 8) | x0c) << 7) | 1);
        prmi[tap][pp][1] = (iy0 && ix1) ? ((ry0 * 20 + rx1) << 7) : ((((y0c << 8) | x1c) << 7) | 1);
        prmi[tap][pp][2] = (iy1 && ix0) ? ((ry1 * 20 + rx0) << 7) : ((((y1c << 8) | x0c) << 7) | 1);
        prmi[tap][pp][3] = (iy1 && ix1) ? ((ry1 * 20 + rx1) << 7) : ((((y1c << 8) | x1c) << 7) | 1);
    }
    __syncthreads();
    // ---- main loop: waves independent, zero barriers ----

    f32x4 z = {0.f, 0.f, 0.f, 0.f};
    f32x4 acc[4] = {z, z, z, z};
    const short8* ap = (const short8*)wApack;
    int coff = lhi << 4;

#define CORNER(IV, W)                                                          \
    {                                                                          \
        int iv = (IV);                                                         \
        bool g = (iv & 1);                                                     \
        unsigned long long mg = __ballot(g);                                   \
        int la = g ? 0 : iv;                                                   \
        int c7 = (la >> 7) & 7;                                                \
        uint4 q0 = *(const uint4*)(halo + la + ((lhi ^ c7) << 4));             \
        uint4 q1 = *(const uint4*)(halo + la + (((4 + lhi) ^ c7) << 4));       \
        if (mg) {                                                              \
            if (g) {                                                           \
                const char* ga = xbb + (((size_t)((unsigned)iv >> 7)) << 7) + coff; \
                q0 = *(const uint4*)ga;                                        \
                q1 = *(const uint4*)(ga + 64);                                 \
            }                                                                  \
        }                                                                      \
        acc_corner(q0, (W), v0);                                               \
        acc_corner(q1, (W), v1);                                               \
    }

#pragma unroll
    for (int tap = 0; tap < 9; ++tap) {
        short8 a[8];
#pragma unroll
        for (int u = 0; u < 8; ++u)
            a[u] = ap[(((u >> 1) * 9 + tap) * 2 + (u & 1)) * 64 + lane];
        float4 wv = *(float4*)&prmw[tap][p][0];
        int4 ip = *(int4*)&prmi[tap][p][0];
        float v0[8] = {0.f, 0.f, 0.f, 0.f, 0.f, 0.f, 0.f, 0.f};
        float v1[8] = {0.f, 0.f, 0.f, 0.f, 0.f, 0.f, 0.f, 0.f};
        CORNER(ip.x, wv.x);
        CORNER(ip.y, wv.y);
        CORNER(ip.z, wv.z);
        CORNER(ip.w, wv.w);
        short8 b0 = pack8(v0);
        short8 b1 = pack8(v1);
#pragma unroll
        for (int g2 = 0; g2 < 4; ++g2) {
            acc[g2] = __builtin_amdgcn_mfma_f32_16x16x32_bf16(a[g2 * 2 + 0], b0, acc[g2], 0, 0, 0);
            acc[g2] = __builtin_amdgcn_mfma_f32_16x16x32_bf16(a[g2 * 2 + 1], b1, acc[g2], 0, 0, 0);
        }
    }
#undef CORNER

    // epilogue: preout (bf16, NCHW)
    unsigned short* pob = preout + (size_t)b * 64 * HWSZ;
    int gp = (h0 + (p >> 3)) * IMGW + w0 + (p & 7);
#pragma unroll
    for (int g2 = 0; g2 < 4; ++g2) {
#pragma unroll
        for (int jj = 0; jj < 4; ++jj) {
            int o = g2 * 16 + lhi * 4 + jj;
            pob[(size_t)o * HWSZ + gp] = f2bf(acc[g2][jj]);
        }
    }
    // BN partial stats
#pragma unroll
    for (int g2 = 0; g2 < 4; ++g2) {
#pragma unroll
        for (int jj = 0; jj < 4; ++jj) {
            float s1 = acc[g2][jj];
            float s2 = s1 * s1;
#pragma unroll
            for (int mask = 1; mask < 16; mask <<= 1) {
                s1 += __shfl_xor(s1, mask);
                s2 += __shfl_xor(s2, mask);
            }
            if (lp == 0) {
                int o = g2 * 16 + lhi * 4 + jj;
                atomicAdd(&bstats[o], s1);
                atomicAdd(&bstats[64 + o], s2);
            }
        }
    }
    __syncthreads();
    if (t < 128) atomicAdd(&stats[t], bstats[t]);
}

// ---------------- K3: normalize + relu + residual ----------------
__global__ __launch_bounds__(256) void bn_finalize(const float* __restrict__ stats,
                                                   const float* __restrict__ gamma,
                                                   const float* __restrict__ beta,
                                                   const float* __restrict__ x,
                                                   const unsigned short* __restrict__ preout,
                                                   float* __restrict__ out) {
    int i = blockIdx.x * 256 + threadIdx.x;     // uint4 idx over 8.4M bf16
    int e0 = i * 8;
    int o = (e0 >> 16) & 63;
    const float inv_n = 1.f / 131072.f;
    float mean = stats[o] * inv_n;
    float var = stats[64 + o] * inv_n - mean * mean;
    float rstd = rsqrtf(var + 1e-5f);
    float g = gamma[o] * rstd;
    float bb = beta[o] - mean * g;
    uint4 q = ((const uint4*)preout)[i];
    float4 x0 = ((const float4*)x)[i * 2];
    float4 x1 = ((const float4*)x)[i * 2 + 1];
    float4 r0, r1;
    r0.x = fmaxf(__uint_as_float(q.x << 16) * g + bb, 0.f) + x0.x;
    r0.y = fmaxf(__uint_as_float(q.x & 0xffff0000u) * g + bb, 0.f) + x0.y;
    r0.z = fmaxf(__uint_as_float(q.y << 16) * g + bb, 0.f) + x0.z;
    r0.w = fmaxf(__uint_as_float(q.y & 0xffff0000u) * g + bb, 0.f) + x0.w;
    r1.x = fmaxf(__uint_as_float(q.z << 16) * g + bb, 0.f) + x1.x;
    r1.y = fmaxf(__uint_as_float(q.z & 0xffff0000u) * g + bb, 0.f) + x1.y;
    r1.z = fmaxf(__uint_as_float(q.w << 16) * g + bb, 0.f) + x1.z;
    r1.w = fmaxf(__uint_as_float(q.w & 0xffff0000u) * g + bb, 0.f) + x1.w;
    ((float4*)out)[i * 2] = r0;
    ((float4*)out)[i * 2 + 1] = r1;
}

extern "C" void kernel_launch(void* const* d_in, const int* in_sizes, int n_in,
                              void* d_out, int out_size, void* d_ws, size_t ws_size,
                              hipStream_t stream) {
    const float* x     = (const float*)d_in[0];
    const float* w_off = (const float*)d_in[1];
    const float* b_off = (const float*)d_in[2];
    const float* w     = (const float*)d_in[3];
    const float* gamma = (const float*)d_in[5];
    const float* beta  = (const float*)d_in[6];
    float* out = (float*)d_out;
    char* wsb = (char*)d_ws;

    unsigned short* xT       = (unsigned short*)wsb;                    // 16,777,216 B
    float*          om       = (float*)(wsb + 16777216);                // 14,155,776 B
    unsigned short* preout   = (unsigned short*)(wsb + 30932992);       // 16,777,216 B
    unsigned short* wApack   = (unsigned short*)(wsb + 47710208);       // 73,728 B
    unsigned short* wOffPack = (unsigned short*)(wsb + 47783936);       // 36,864 B
    float*          stats    = (float*)(wsb + 47820800);                // 512 B

    hipMemsetAsync(stats, 0, 512, stream);
    prep_weights<<<216, 256, 0, stream>>>(w_off, w, wApack, wOffPack);
    transpose_x<<<2048, 256, 0, stream>>>(x, xT);
    offset_conv<<<2048, 256, 0, stream>>>(xT, wOffPack, b_off, om);
    dcn_main<<<2048, 256, 0, stream>>>(xT, om, wApack, preout, stats);
    bn_finalize<<<4096, 256, 0, stream>>>(stats, gamma, beta, x, preout, out);
}

// Round 6
// 121.232 us; speedup vs baseline: 3.6356x; 1.1270x over previous
//
#include <hip/hip_runtime.h>
#include <hip/hip_fp16.h>
#include <math.h>

#define HWSZ 65536   // 256*256
#define IMGH 256
#define IMGW 256

typedef _Float16 half8 __attribute__((ext_vector_type(8)));
typedef float f32x4 __attribute__((ext_vector_type(4)));

__device__ inline unsigned short f2bf(float f) {
    unsigned u = __float_as_uint(f);
    return (unsigned short)((u + 0x7fffu + ((u >> 16) & 1u)) >> 16);
}
__device__ inline unsigned short f2h(float f) {
    __half h = __float2half(f);
    return __half_as_ushort(h);
}
__device__ inline __half2 duph2(unsigned s) {
    union { unsigned u; __half2 h; } c;
    c.u = (s & 0xffffu) * 0x10001u;
    return c.h;
}
__device__ inline void hacc(const uint4& q, __half2 w, __half2* v) {
    const __half2* h = (const __half2*)&q;
    v[0] = __hfma2(h[0], w, v[0]);
    v[1] = __hfma2(h[1], w, v[1]);
    v[2] = __hfma2(h[2], w, v[2]);
    v[3] = __hfma2(h[3], w, v[3]);
}

// ---------------- K0a: pack MFMA A-fragments (fp16) ----------------
__global__ void prep_weights(const float* __restrict__ w_off,
                             const float* __restrict__ w,
                             unsigned short* __restrict__ wApack,
                             unsigned short* __restrict__ wOffPack) {
    int i = blockIdx.x * 256 + threadIdx.x;
    if (i < 36864) {
        int e = i;
        int j = e & 7, lane = (e >> 3) & 63, kk = (e >> 9) & 1;
        int t2 = e >> 10;
        int tap = t2 % 9, g = t2 / 9;
        int o = g * 16 + (lane & 15);
        int c = kk * 32 + ((lane >> 4) & 3) * 8 + j;
        wApack[e] = f2h(w[(o * 64 + c) * 9 + tap]);
    } else if (i < 36864 + 18432) {
        int e = i - 36864;
        int j = e & 7, lane = (e >> 3) & 63, kk = (e >> 9) & 1;
        int t2 = e >> 10;
        int tap = t2 % 9, mt = t2 / 9;
        int d = mt * 16 + (lane & 15);
        int c = kk * 32 + ((lane >> 4) & 3) * 8 + j;
        float v = (d < 27) ? w_off[(d * 64 + c) * 9 + tap] : 0.f;
        wOffPack[e] = f2h(v);
    }
}

// ---------------- K0b: x NCHW fp32 -> NHWC fp16 ----------------
__global__ __launch_bounds__(256) void transpose_x(const float* __restrict__ x,
                                                   unsigned short* __restrict__ xT) {
    __shared__ float tile[64 * 65];
    int blk = blockIdx.x;              // 2048 = 2 * 1024
    int b = blk >> 10;
    int p0 = (blk & 1023) * 64;
    int t = threadIdx.x;
    const float* xb = x + (size_t)b * 64 * HWSZ;
    unsigned short* xTb = xT + (size_t)b * HWSZ * 64;
    int pp = t & 63;
    int c0r = t >> 6;
#pragma unroll
    for (int i = 0; i < 16; ++i) {
        int c = c0r + 4 * i;
        tile[c * 65 + pp] = xb[(size_t)c * HWSZ + p0 + pp];
    }
    __syncthreads();
#pragma unroll
    for (int it = 0; it < 2; ++it) {
        int item = t + it * 256;       // 512 items
        int p = item >> 3;
        int c0 = (item & 7) * 8;
        uint4 ow;
        ow.x = f2h(tile[(c0 + 0) * 65 + p]) | ((unsigned)f2h(tile[(c0 + 1) * 65 + p]) << 16);
        ow.y = f2h(tile[(c0 + 2) * 65 + p]) | ((unsigned)f2h(tile[(c0 + 3) * 65 + p]) << 16);
        ow.z = f2h(tile[(c0 + 4) * 65 + p]) | ((unsigned)f2h(tile[(c0 + 5) * 65 + p]) << 16);
        ow.w = f2h(tile[(c0 + 6) * 65 + p]) | ((unsigned)f2h(tile[(c0 + 7) * 65 + p]) << 16);
        *(uint4*)&xTb[(size_t)(p0 + p) * 64 + c0] = ow;
    }
}

// ---------------- K1: offset conv via MFMA (fp16) -> om[b][d][p] ----------------
__global__ __launch_bounds__(256) void offset_conv(const unsigned short* __restrict__ xT,
                                                   const unsigned short* __restrict__ wOffPack,
                                                   const float* __restrict__ b_off,
                                                   float* __restrict__ om) {
    __shared__ uint4 haloBuf[800];     // 10x10 cells x 64ch fp16, swizzled
    char* halo = (char*)haloBuf;
    int bid = blockIdx.x;              // 2048
    int blk = ((bid & 7) << 8) | (bid >> 3);   // XCD-chunked swizzle
    int b = blk >> 10;
    int tb = blk & 1023;
    int ty = tb >> 5, tx = tb & 31;
    int h0 = ty * 8, w0 = tx * 8;
    int t = threadIdx.x;
    const char* xbb = (const char*)(xT + (size_t)b * HWSZ * 64);

    for (int i = t; i < 800; i += 256) {
        int cell = i >> 3;
        int c0 = (i & 7) * 8;
        int r = cell / 10, s = cell - r * 10;
        int y = h0 - 1 + r, xx = w0 - 1 + s;
        uint4 v = {0u, 0u, 0u, 0u};
        if (y >= 0 && y < IMGH && xx >= 0 && xx < IMGW)
            v = *(const uint4*)(xbb + ((size_t)(y * IMGW + xx) << 7) + (c0 << 1));
        *(uint4*)(halo + (cell << 7) + (((c0 << 1)) ^ ((cell & 7) << 4))) = v;
    }
    __syncthreads();

    int lane = t & 63;
    int wid = __builtin_amdgcn_readfirstlane(t >> 6);
    int mt = wid & 1;
    int np = wid >> 1;
    f32x4 z = {0.f, 0.f, 0.f, 0.f};
    f32x4 acc[2] = {z, z};
    int lhi = lane >> 4;

    for (int tap = 0; tap < 9; ++tap) {
        const half8* ap = (const half8*)wOffPack;
        half8 a0 = ap[((mt * 9 + tap) * 2 + 0) * 64 + lane];
        half8 a1 = ap[((mt * 9 + tap) * 2 + 1) * 64 + lane];
        int dy = tap / 3, dx = tap - dy * 3;
#pragma unroll
        for (int nn = 0; nn < 2; ++nn) {
            int p = (np * 2 + nn) * 16 + (lane & 15);
            int cell = ((p >> 3) + dy) * 10 + (p & 7) + dx;
            int base = (cell << 7);
            int swz = (cell & 7) << 4;
            half8 b0 = *(const half8*)(halo + base + ((lhi << 4) ^ swz));
            acc[nn] = __builtin_amdgcn_mfma_f32_16x16x32_f16(a0, b0, acc[nn], 0, 0, 0);
            half8 b1 = *(const half8*)(halo + base + (((4 + lhi) << 4) ^ swz));
            acc[nn] = __builtin_amdgcn_mfma_f32_16x16x32_f16(a1, b1, acc[nn], 0, 0, 0);
        }
    }
    float* omb = om + (size_t)b * 27 * HWSZ;
#pragma unroll
    for (int nn = 0; nn < 2; ++nn) {
#pragma unroll
        for (int jj = 0; jj < 4; ++jj) {
            int d = mt * 16 + lhi * 4 + jj;
            if (d < 27) {
                int p = (np * 2 + nn) * 16 + (lane & 15);
                int gp = (h0 + (p >> 3)) * IMGW + w0 + (p & 7);
                omb[(size_t)d * HWSZ + gp] = acc[nn][jj] + b_off[d];
            }
        }
    }
}

// ---------------- K2: LDS-halo deformable sample (fp16) + MFMA einsum ----------------
// Halo 18x18 px x 64ch fp16 (rows h0-5..h0+12), chunk-XOR swizzled. Compact prmi
// encodes halo cell (bit0=0) or raw signed coords (bit0=1 -> rare global fallback).
__global__ __launch_bounds__(256, 3) void dcn_main(const unsigned short* __restrict__ xT,
                                                   const float* __restrict__ om,
                                                   const unsigned short* __restrict__ wApack,
                                                   unsigned short* __restrict__ preout,
                                                   float* __restrict__ stats) {
    __shared__ uint4 haloBuf[2592];    // 324 cells x 128B = 41472 B
    __shared__ unsigned prmi[9][64];   // 2304 B
    __shared__ uint2 prmw[9][64];      // 4608 B (4 x fp16 weights)
    __shared__ float bstats[128];      // 512 B
    char* halo = (char*)haloBuf;
    int bid = blockIdx.x;              // 2048
    int blk = ((bid & 7) << 8) | (bid >> 3);   // XCD-chunked swizzle
    int b = blk >> 10;
    int tb = blk & 1023;
    int ty = tb >> 5, tx = tb & 31;
    int h0 = ty * 8, w0 = tx * 8;
    int t = threadIdx.x;
    const char* xbb = (const char*)(xT + (size_t)b * HWSZ * 64);
    const float* omb = om + (size_t)b * 27 * HWSZ;
    int lane = t & 63;
    int wid = t >> 6;
    int lp = lane & 15;
    int lhi = lane >> 4;
    int p = wid * 16 + lp;
    int hb = h0 - 5, wb = w0 - 5;

    if (t < 128) bstats[t] = 0.f;

    // stage halo: 324 cells x 8 chunks, chunk ch stored at slot ch^(cell&7)
    for (int i = t; i < 2592; i += 256) {
        int cell = i >> 3;
        int ch = i & 7;
        int r = cell / 18, c = cell - r * 18;
        int y = hb + r, xx = wb + c;
        uint4 v = {0u, 0u, 0u, 0u};
        if ((unsigned)y < 256u && (unsigned)xx < 256u)
            v = *(const uint4*)(xbb + ((size_t)((y << 8) + xx) << 7) + (ch << 4));
        *(uint4*)(halo + (cell << 7) + ((ch ^ (cell & 7)) << 4)) = v;
    }

    // bilinear params for all 9 taps
    for (int i = t; i < 576; i += 256) {
        int tap = i >> 6, pp = i & 63;
        int h = h0 + (pp >> 3), wc = w0 + (pp & 7);
        int gp = h * IMGW + wc;
        float offy = omb[(size_t)tap * HWSZ + gp];
        float offx = omb[(size_t)(tap + 9) * HWSZ + gp];
        float mraw = omb[(size_t)(tap + 18) * HWSZ + gp];
        float m = 1.f / (1.f + __expf(-mraw));
        float pyf = (float)(h + tap / 3 - 1) + offy;
        float pxf = (float)(wc + tap % 3 - 1) + offx;
        float y0f = floorf(pyf), x0f = floorf(pxf);
        float wy = pyf - y0f, wx = pxf - x0f;
        int y0 = (int)y0f, x0 = (int)x0f;
        int y1 = y0 + 1, x1 = x0 + 1;
        float vy0 = (y0 >= 0 && y0 < IMGH) ? 1.f : 0.f;
        float vy1 = (y1 >= 0 && y1 < IMGH) ? 1.f : 0.f;
        float vx0 = (x0 >= 0 && x0 < IMGW) ? 1.f : 0.f;
        float vx1 = (x1 >= 0 && x1 < IMGW) ? 1.f : 0.f;
        float w00 = (1.f - wy) * (1.f - wx) * m * vy0 * vx0;
        float w01 = (1.f - wy) * wx * m * vy0 * vx1;
        float w10 = wy * (1.f - wx) * m * vy1 * vx0;
        float w11 = wy * wx * m * vy1 * vx1;
        prmw[tap][pp] = make_uint2((unsigned)f2h(w00) | ((unsigned)f2h(w01) << 16),
                                   (unsigned)f2h(w10) | ((unsigned)f2h(w11) << 16));
        int ry0 = y0 - hb, rx0 = x0 - wb;
        unsigned enc;
        if ((unsigned)ry0 <= 16u && (unsigned)rx0 <= 16u) {
            enc = (unsigned)((ry0 * 18 + rx0) << 7);            // bit0 = 0
        } else {
            int y0s = min(max(y0, -8), 383) + 8;                // 9 bits
            int x0s = min(max(x0, -8), 383) + 8;
            enc = 1u | ((unsigned)y0s << 1) | ((unsigned)x0s << 10);
        }
        prmi[tap][pp] = enc;
    }
    __syncthreads();
    // ---- main loop: waves independent, zero barriers ----

    f32x4 z = {0.f, 0.f, 0.f, 0.f};
    f32x4 acc[4] = {z, z, z, z};
    const half8* ap = (const half8*)wApack;
    uint4 q[4][2];                     // [corner][kk]

#define LOADC(PI)                                                             \
    {                                                                         \
        unsigned pi_ = (PI);                                                  \
        bool fb_ = (pi_ & 1u);                                                \
        unsigned base_ = fb_ ? 0u : pi_;                                      \
        unsigned o00 = base_, o01 = base_ + 128u,                             \
                 o10 = base_ + 2304u, o11 = base_ + 2432u;                    \
        q[0][0] = *(const uint4*)(halo + o00 + ((lhi ^ ((o00 >> 7) & 7)) << 4));       \
        q[0][1] = *(const uint4*)(halo + o00 + (((4 + lhi) ^ ((o00 >> 7) & 7)) << 4)); \
        q[1][0] = *(const uint4*)(halo + o01 + ((lhi ^ ((o01 >> 7) & 7)) << 4));       \
        q[1][1] = *(const uint4*)(halo + o01 + (((4 + lhi) ^ ((o01 >> 7) & 7)) << 4)); \
        q[2][0] = *(const uint4*)(halo + o10 + ((lhi ^ ((o10 >> 7) & 7)) << 4));       \
        q[2][1] = *(const uint4*)(halo + o10 + (((4 + lhi) ^ ((o10 >> 7) & 7)) << 4)); \
        q[3][0] = *(const uint4*)(halo + o11 + ((lhi ^ ((o11 >> 7) & 7)) << 4));       \
        q[3][1] = *(const uint4*)(halo + o11 + (((4 + lhi) ^ ((o11 >> 7) & 7)) << 4)); \
        if (__ballot(fb_)) {                                                  \
            if (fb_) {                                                        \
                int y0r = (int)((pi_ >> 1) & 511) - 8;                        \
                int x0r = (int)((pi_ >> 10) & 511) - 8;                       \
                int y0c = min(max(y0r, 0), 255), y1c = min(max(y0r + 1, 0), 255); \
                int x0c = min(max(x0r, 0), 255), x1c = min(max(x0r + 1, 0), 255); \
                const char* g00 = xbb + (((y0c << 8) + x0c) << 7) + (lhi << 4); \
                const char* g01 = xbb + (((y0c << 8) + x1c) << 7) + (lhi << 4); \
                const char* g10 = xbb + (((y1c << 8) + x0c) << 7) + (lhi << 4); \
                const char* g11 = xbb + (((y1c << 8) + x1c) << 7) + (lhi << 4); \
                q[0][0] = *(const uint4*)g00; q[0][1] = *(const uint4*)(g00 + 64); \
                q[1][0] = *(const uint4*)g01; q[1][1] = *(const uint4*)(g01 + 64); \
                q[2][0] = *(const uint4*)g10; q[2][1] = *(const uint4*)(g10 + 64); \
                q[3][0] = *(const uint4*)g11; q[3][1] = *(const uint4*)(g11 + 64); \
            }                                                                 \
        }                                                                     \
    }

    unsigned pi = prmi[0][p];
    uint2 ww = prmw[0][p];
    LOADC(pi);

#pragma unroll
    for (int tap = 0; tap < 9; ++tap) {
        __half2 W00 = duph2(ww.x), W01 = duph2(ww.x >> 16);
        __half2 W10 = duph2(ww.y), W11 = duph2(ww.y >> 16);
        union HV { __half2 h2[4]; half8 h8; } V0, V1;
        __half2 z2 = __float2half2_rn(0.f);
#pragma unroll
        for (int j = 0; j < 4; ++j) { V0.h2[j] = z2; V1.h2[j] = z2; }
        hacc(q[0][0], W00, V0.h2); hacc(q[0][1], W00, V1.h2);
        hacc(q[1][0], W01, V0.h2); hacc(q[1][1], W01, V1.h2);
        hacc(q[2][0], W10, V0.h2); hacc(q[2][1], W10, V1.h2);
        hacc(q[3][0], W11, V0.h2); hacc(q[3][1], W11, V1.h2);
        half8 b0 = V0.h8, b1 = V1.h8;
        if (tap < 8) {                 // prefetch next tap's corners (LDS, lgkm)
            pi = prmi[tap + 1][p];
            ww = prmw[tap + 1][p];
            LOADC(pi);
        }
#pragma unroll
        for (int g2 = 0; g2 < 4; ++g2) {
            half8 a0 = ap[((g2 * 9 + tap) * 2 + 0) * 64 + lane];
            half8 a1 = ap[((g2 * 9 + tap) * 2 + 1) * 64 + lane];
            acc[g2] = __builtin_amdgcn_mfma_f32_16x16x32_f16(a0, b0, acc[g2], 0, 0, 0);
            acc[g2] = __builtin_amdgcn_mfma_f32_16x16x32_f16(a1, b1, acc[g2], 0, 0, 0);
        }
    }
#undef LOADC

    // epilogue: preout (bf16, NCHW)
    unsigned short* pob = preout + (size_t)b * 64 * HWSZ;
    int gp = (h0 + (p >> 3)) * IMGW + w0 + (p & 7);
#pragma unroll
    for (int g2 = 0; g2 < 4; ++g2) {
#pragma unroll
        for (int jj = 0; jj < 4; ++jj) {
            int o = g2 * 16 + lhi * 4 + jj;
            pob[(size_t)o * HWSZ + gp] = f2bf(acc[g2][jj]);
        }
    }
    // BN partial stats
#pragma unroll
    for (int g2 = 0; g2 < 4; ++g2) {
#pragma unroll
        for (int jj = 0; jj < 4; ++jj) {
            float s1 = acc[g2][jj];
            float s2 = s1 * s1;
#pragma unroll
            for (int mask = 1; mask < 16; mask <<= 1) {
                s1 += __shfl_xor(s1, mask);
                s2 += __shfl_xor(s2, mask);
            }
            if (lp == 0) {
                int o = g2 * 16 + lhi * 4 + jj;
                atomicAdd(&bstats[o], s1);
                atomicAdd(&bstats[64 + o], s2);
            }
        }
    }
    __syncthreads();
    if (t < 128) atomicAdd(&stats[t], bstats[t]);
}

// ---------------- K3: normalize + relu + residual ----------------
__global__ __launch_bounds__(256) void bn_finalize(const float* __restrict__ stats,
                                                   const float* __restrict__ gamma,
                                                   const float* __restrict__ beta,
                                                   const float* __restrict__ x,
                                                   const unsigned short* __restrict__ preout,
                                                   float* __restrict__ out) {
    int i = blockIdx.x * 256 + threadIdx.x;     // uint4 idx over 8.4M bf16
    int e0 = i * 8;
    int o = (e0 >> 16) & 63;
    const float inv_n = 1.f / 131072.f;
    float mean = stats[o] * inv_n;
    float var = stats[64 + o] * inv_n - mean * mean;
    float rstd = rsqrtf(var + 1e-5f);
    float g = gamma[o] * rstd;
    float bb = beta[o] - mean * g;
    uint4 q = ((const uint4*)preout)[i];
    float4 x0 = ((const float4*)x)[i * 2];
    float4 x1 = ((const float4*)x)[i * 2 + 1];
    float4 r0, r1;
    r0.x = fmaxf(__uint_as_float(q.x << 16) * g + bb, 0.f) + x0.x;
    r0.y = fmaxf(__uint_as_float(q.x & 0xffff0000u) * g + bb, 0.f) + x0.y;
    r0.z = fmaxf(__uint_as_float(q.y << 16) * g + bb, 0.f) + x0.z;
    r0.w = fmaxf(__uint_as_float(q.y & 0xffff0000u) * g + bb, 0.f) + x0.w;
    r1.x = fmaxf(__uint_as_float(q.z << 16) * g + bb, 0.f) + x1.x;
    r1.y = fmaxf(__uint_as_float(q.z & 0xffff0000u) * g + bb, 0.f) + x1.y;
    r1.z = fmaxf(__uint_as_float(q.w << 16) * g + bb, 0.f) + x1.z;
    r1.w = fmaxf(__uint_as_float(q.w & 0xffff0000u) * g + bb, 0.f) + x1.w;
    ((float4*)out)[i * 2] = r0;
    ((float4*)out)[i * 2 + 1] = r1;
}

extern "C" void kernel_launch(void* const* d_in, const int* in_sizes, int n_in,
                              void* d_out, int out_size, void* d_ws, size_t ws_size,
                              hipStream_t stream) {
    const float* x     = (const float*)d_in[0];
    const float* w_off = (const float*)d_in[1];
    const float* b_off = (const float*)d_in[2];
    const float* w     = (const float*)d_in[3];
    const float* gamma = (const float*)d_in[5];
    const float* beta  = (const float*)d_in[6];
    float* out = (float*)d_out;
    char* wsb = (char*)d_ws;

    unsigned short* xT       = (unsigned short*)wsb;                    // 16,777,216 B (fp16)
    float*          om       = (float*)(wsb + 16777216);                // 14,155,776 B
    unsigned short* preout   = (unsigned short*)(wsb + 30932992);       // 16,777,216 B (bf16)
    unsigned short* wApack   = (unsigned short*)(wsb + 47710208);       // 73,728 B (fp16)
    unsigned short* wOffPack = (unsigned short*)(wsb + 47783936);       // 36,864 B (fp16)
    float*          stats    = (float*)(wsb + 47820800);                // 512 B

    hipMemsetAsync(stats, 0, 512, stream);
    prep_weights<<<216, 256, 0, stream>>>(w_off, w, wApack, wOffPack);
    transpose_x<<<2048, 256, 0, stream>>>(x, xT);
    offset_conv<<<2048, 256, 0, stream>>>(xT, wOffPack, b_off, om);
    dcn_main<<<2048, 256, 0, stream>>>(xT, om, wApack, preout, stats);
    bn_finalize<<<4096, 256, 0, stream>>>(stats, gamma, beta, x, preout, out);
}